// Round 15
// baseline (299.890 us; speedup 1.0000x reference)
//
#include <hip/hip_runtime.h>
#include <hip/hip_bf16.h>

// GATv2 x2 on MI355X — MFMA gemm1 (split-bf16), bf16 xl1 gather, DPP reduce.
// R15: node kernels made WAVE-INDEPENDENT (no LDS staging, no syncthreads):
//  R14 profile showed occupancy 52% — 10000 micro-blocks (1 node = 2.2 chunk
//  iters) with barrier-coupled waves drain CUs. ssrc is 1.3 MB and each
//  chunk's 16 indices are one 64B cache line, so LDS staging bought nothing.
//  Now: wave = 4 consecutive (node,head) pairs (layer1) / 4 nodes (layer2);
//  waves issue/retire independently, ~9 chunk-iters each, offsets prefetched.

constexpr int N_NODES = 10000;
constexpr int N_EDGES = 320000;
constexpr int ET      = N_EDGES + N_NODES;   // 330000 incl. self loops
constexpr float NEG_SLOPE = 0.2f;

constexpr int NB_COUNT = (ET + 255) / 256;          // 1290
constexpr int NB_CONVX = (N_NODES * 64) / 256;      // 2500
constexpr int NB_CONVW = (1024 * 64) / 256;         // 256

typedef __attribute__((ext_vector_type(8))) short short8;
typedef __attribute__((ext_vector_type(8))) unsigned short ushort8_t;
typedef __attribute__((ext_vector_type(4))) float floatx4;

__device__ __forceinline__ float lrelu(float a) {
    return fmaxf(a, NEG_SLOPE * a);
}
__device__ __forceinline__ unsigned short f2bf(float f) {   // RNE
    unsigned u = __float_as_uint(f);
    unsigned r = u + 0x7FFFu + ((u >> 16) & 1u);
    return (unsigned short)(r >> 16);
}
__device__ __forceinline__ float bf2f(unsigned short h) {
    return __uint_as_float((unsigned)h << 16);
}
// sum over each aligned group of 8 lanes, result in all 8 (pure VALU)
__device__ __forceinline__ float red8_dpp(float p) {
    int x;
    x = __builtin_amdgcn_update_dpp(0, __float_as_int(p), 0xB1, 0xF, 0xF, true);
    p += __int_as_float(x);                  // quad_perm [1,0,3,2]
    x = __builtin_amdgcn_update_dpp(0, __float_as_int(p), 0x4E, 0xF, 0xF, true);
    p += __int_as_float(x);                  // quad_perm [2,3,0,1]
    x = __builtin_amdgcn_update_dpp(0, __float_as_int(p), 0x141, 0xF, 0xF, true);
    p += __int_as_float(x);                  // row_half_mirror
    return p;
}
__device__ __forceinline__ float red8max_dpp(float p) {
    int x;
    x = __builtin_amdgcn_update_dpp(0, __float_as_int(p), 0xB1, 0xF, 0xF, true);
    p = fmaxf(p, __int_as_float(x));
    x = __builtin_amdgcn_update_dpp(0, __float_as_int(p), 0x4E, 0xF, 0xF, true);
    p = fmaxf(p, __int_as_float(x));
    x = __builtin_amdgcn_update_dpp(0, __float_as_int(p), 0x141, 0xF, 0xF, true);
    p = fmaxf(p, __int_as_float(x));
    return p;
}
// pairwise add with lane^8 partner (row_ror:8 within 16-lane rows)
__device__ __forceinline__ float ror8_add(float p) {
    int x = __builtin_amdgcn_update_dpp(0, __float_as_int(p), 0x128, 0xF, 0xF, true);
    return p + __int_as_float(x);
}

// ---------------- fused prep: deg count + conv_x + conv_w ----------------

__global__ __launch_bounds__(256) void k_prep(const int* __restrict__ ei,
        int* __restrict__ deg, const float* __restrict__ x,
        unsigned short* __restrict__ A, const float* __restrict__ Wl,
        const float* __restrict__ Wr, unsigned short* __restrict__ Bt) {
    int b = blockIdx.x, t = threadIdx.x;
    if (b < NB_COUNT) {
        int e = b * 256 + t;
        if (e >= ET) return;
        int d = (e < N_EDGES) ? ei[N_EDGES + e] : (e - N_EDGES);
        atomicAdd(&deg[d], 1);
    } else if (b < NB_COUNT + NB_CONVX) {
        int idx = (b - NB_COUNT) * 256 + t;       // < N_NODES*64
        int m = idx >> 6, kg = (idx & 63) << 2;
        float4 v = *reinterpret_cast<const float4*>(x + (size_t)m * 256 + kg);
        ushort4 hi = make_ushort4(f2bf(v.x), f2bf(v.y), f2bf(v.z), f2bf(v.w));
        ushort4 lo = make_ushort4(f2bf(v.x - bf2f(hi.x)), f2bf(v.y - bf2f(hi.y)),
                                  f2bf(v.z - bf2f(hi.z)), f2bf(v.w - bf2f(hi.w)));
        size_t base = (size_t)m * 768 + kg;
        *reinterpret_cast<ushort4*>(A + base)       = hi;
        *reinterpret_cast<ushort4*>(A + base + 256) = lo;
        *reinterpret_cast<ushort4*>(A + base + 512) = hi;
    } else {
        int idx = (b - NB_COUNT - NB_CONVX) * 256 + t;   // < 1024*64
        int n = idx >> 6, kg = (idx & 63) << 2;
        const float* src = (n < 512) ? (Wl + n) : (Wr + (n - 512));
        float v0 = src[(size_t)(kg + 0) * 512];
        float v1 = src[(size_t)(kg + 1) * 512];
        float v2 = src[(size_t)(kg + 2) * 512];
        float v3 = src[(size_t)(kg + 3) * 512];
        ushort4 hi = make_ushort4(f2bf(v0), f2bf(v1), f2bf(v2), f2bf(v3));
        ushort4 lo = make_ushort4(f2bf(v0 - bf2f(hi.x)), f2bf(v1 - bf2f(hi.y)),
                                  f2bf(v2 - bf2f(hi.z)), f2bf(v3 - bf2f(hi.w)));
        size_t base = (size_t)n * 768 + kg;
        *reinterpret_cast<ushort4*>(Bt + base)       = hi;
        *reinterpret_cast<ushort4*>(Bt + base + 256) = hi;
        *reinterpret_cast<ushort4*>(Bt + base + 512) = lo;
    }
}

// ---------------- CSR scan + scatter ----------------

__global__ __launch_bounds__(1024) void k_scan(const int* __restrict__ deg,
                                               int* __restrict__ offs) {
    __shared__ int part[1024];
    const int CH = 10;                       // ceil(10000/1024)
    int t = threadIdx.x;
    int base = t * CH;
    int loc[CH];
    int s = 0;
    for (int i = 0; i < CH; ++i) {
        int idx = base + i;
        int v = (idx < N_NODES) ? deg[idx] : 0;
        loc[i] = s; s += v;
    }
    part[t] = s;
    __syncthreads();
    for (int o = 1; o < 1024; o <<= 1) {
        int add = (t >= o) ? part[t - o] : 0;
        __syncthreads();
        part[t] += add;
        __syncthreads();
    }
    int excl = part[t] - s;
    for (int i = 0; i < CH; ++i) {
        int idx = base + i;
        if (idx < N_NODES) offs[idx] = excl + loc[i];
    }
    if (t == 1023) offs[N_NODES] = part[1023];
}

// deg doubles as countdown cursor: pos = offs[d] + (--deg[d])
__global__ void k_scatter(const int* __restrict__ ei, const int* __restrict__ offs,
                          int* __restrict__ deg, int* __restrict__ ssrc) {
    int e = blockIdx.x * 256 + threadIdx.x;
    if (e >= ET) return;
    int s, d;
    if (e < N_EDGES) { s = ei[e]; d = ei[N_EDGES + e]; }
    else             { s = d = e - N_EDGES; }
    int pos = offs[d] + atomicAdd(&deg[d], -1) - 1;
    ssrc[pos] = s;
}

// ---------------- layer 1 MFMA GEMM ----------------

// 128x128 tile, M=10000 N=1024 K=768, grid (79,8), 4 waves/block.
__global__ __launch_bounds__(256) void k_mfma1(const unsigned short* __restrict__ A,
        const unsigned short* __restrict__ Bt, unsigned short* __restrict__ xl1b,
        float* __restrict__ xr1) {
    __shared__ unsigned short As[128 * 40];   // stride 40: 2-way max = free
    __shared__ unsigned short Bs[128 * 40];
    int t = threadIdx.x;
    int wave = t >> 6, L = t & 63;
    int wm = wave & 1, wn = wave >> 1;
    int row0 = blockIdx.x * 128, n0 = blockIdx.y * 128;
    int q = L >> 4, rr = L & 15;
    floatx4 acc[4][4];
#pragma unroll
    for (int i = 0; i < 4; ++i)
#pragma unroll
        for (int j = 0; j < 4; ++j) acc[i][j] = (floatx4){0.f, 0.f, 0.f, 0.f};
    int ra = t >> 2,        ka = (t & 3) * 8;
    int rb = (t + 256) >> 2, kb = ((t + 256) & 3) * 8;
    int gma = row0 + ra; gma = (gma < N_NODES) ? gma : (N_NODES - 1);
    int gmb = row0 + rb; gmb = (gmb < N_NODES) ? gmb : (N_NODES - 1);
    for (int kc = 0; kc < 768; kc += 32) {
        __syncthreads();
        *reinterpret_cast<uint4*>(&As[ra * 40 + ka]) =
            *reinterpret_cast<const uint4*>(A + (size_t)gma * 768 + kc + ka);
        *reinterpret_cast<uint4*>(&As[rb * 40 + kb]) =
            *reinterpret_cast<const uint4*>(A + (size_t)gmb * 768 + kc + kb);
        *reinterpret_cast<uint4*>(&Bs[ra * 40 + ka]) =
            *reinterpret_cast<const uint4*>(Bt + (size_t)(n0 + ra) * 768 + kc + ka);
        *reinterpret_cast<uint4*>(&Bs[rb * 40 + kb]) =
            *reinterpret_cast<const uint4*>(Bt + (size_t)(n0 + rb) * 768 + kc + kb);
        __syncthreads();
        short8 af[4], bf[4];
#pragma unroll
        for (int st = 0; st < 4; ++st)
            af[st] = *reinterpret_cast<const short8*>(
                &As[(wm * 64 + st * 16 + rr) * 40 + q * 8]);
#pragma unroll
        for (int st = 0; st < 4; ++st)
            bf[st] = *reinterpret_cast<const short8*>(
                &Bs[(wn * 64 + st * 16 + rr) * 40 + q * 8]);
#pragma unroll
        for (int i = 0; i < 4; ++i)
#pragma unroll
            for (int j = 0; j < 4; ++j)
                acc[i][j] = __builtin_amdgcn_mfma_f32_16x16x32_bf16(
                    af[i], bf[j], acc[i][j], 0, 0, 0);
    }
    // epilogue: C/D layout col=lane&15, row=(lane>>4)*4+reg  [m89/m91]
#pragma unroll
    for (int j = 0; j < 4; ++j) {
        int gc = n0 + wn * 64 + j * 16 + rr;
        if (gc < 512) {
#pragma unroll
            for (int i = 0; i < 4; ++i)
#pragma unroll
                for (int r = 0; r < 4; ++r) {
                    int gr = row0 + wm * 64 + i * 16 + q * 4 + r;
                    if (gr < N_NODES)
                        xl1b[(size_t)gr * 512 + gc] = f2bf(acc[i][j][r]);
                }
        } else {
            int col = gc - 512;
#pragma unroll
            for (int i = 0; i < 4; ++i)
#pragma unroll
                for (int r = 0; r < 4; ++r) {
                    int gr = row0 + wm * 64 + i * 16 + q * 4 + r;
                    if (gr < N_NODES)
                        xr1[(size_t)gr * 512 + col] = acc[i][j][r];
                }
        }
    }
}

// Fused edge+node layer 1 — wave-independent. Wave = 4 consecutive
// (node,head) pairs (4 heads of one node: ssrc L1 reuse). No LDS, no syncs.
// Lane (ej,cg): edges base+ej / base+8+ej, channels cg*8..+7.
__global__ __launch_bounds__(256) void k_node1f(const int* __restrict__ offs,
        const int* __restrict__ ssrc, const unsigned short* __restrict__ xl1b,
        const float* __restrict__ xr1, const float* __restrict__ att1,
        const float* __restrict__ b1, float* __restrict__ h1) {
    constexpr int NPAIRS = N_NODES * 8;  // 80000
    int t = threadIdx.x;
    int wave = t >> 6, lane = t & 63;
    int ej = lane >> 3;                  // edge slot
    int cg = lane & 7;                   // channel group of 8
    int q = blockIdx.x * 4 + wave;
#pragma unroll 1
    for (int pp = 0; pp < 4; ++pp) {
        int pair = q * 4 + pp;
        if (pair >= NPAIRS) return;
        int n = pair >> 3, h = pair & 7;
        int beg = offs[n], dcnt = offs[n + 1] - beg;
        float xrv[8], atv[8];
        {
            const float* xrrow = xr1 + (size_t)n * 512 + h * 64 + cg * 8;
            const float* atrow = att1 + h * 64 + cg * 8;
            float4 a0 = *reinterpret_cast<const float4*>(xrrow);
            float4 a1 = *reinterpret_cast<const float4*>(xrrow + 4);
            float4 c0 = *reinterpret_cast<const float4*>(atrow);
            float4 c1 = *reinterpret_cast<const float4*>(atrow + 4);
            xrv[0]=a0.x; xrv[1]=a0.y; xrv[2]=a0.z; xrv[3]=a0.w;
            xrv[4]=a1.x; xrv[5]=a1.y; xrv[6]=a1.z; xrv[7]=a1.w;
            atv[0]=c0.x; atv[1]=c0.y; atv[2]=c0.z; atv[3]=c0.w;
            atv[4]=c1.x; atv[5]=c1.y; atv[6]=c1.z; atv[7]=c1.w;
        }
        float l = 0.f;
        float acc8[8];
#pragma unroll
        for (int i = 0; i < 8; ++i) acc8[i] = 0.f;
        const int* sp = ssrc + beg;
        const char* xlbase = reinterpret_cast<const char*>(xl1b)
                           + h * 128 + cg * 16;
        int iA = (ej < dcnt) ? ej : (dcnt - 1);
        int iB = (8 + ej < dcnt) ? 8 + ej : (dcnt - 1);
        int sA = sp[iA] << 10, sB = sp[iB] << 10;
        for (int base = 0; base < dcnt; base += 16) {
            ushort8_t uA = *reinterpret_cast<const ushort8_t*>(xlbase + sA);
            ushort8_t uB = *reinterpret_cast<const ushort8_t*>(xlbase + sB);
            int nA = base + 16 + ej; nA = (nA < dcnt) ? nA : (dcnt - 1);
            int nB = base + 24 + ej; nB = (nB < dcnt) ? nB : (dcnt - 1);
            sA = sp[nA] << 10; sB = sp[nB] << 10;    // prefetch next offsets
            float xsA[8], xsB[8];
#pragma unroll
            for (int i = 0; i < 8; ++i) { xsA[i] = bf2f(uA[i]); xsB[i] = bf2f(uB[i]); }
            float pA0 = 0.f, pA1 = 0.f, pB0 = 0.f, pB1 = 0.f;
#pragma unroll
            for (int i = 0; i < 4; ++i) {
                pA0 += lrelu(xsA[i] + xrv[i]) * atv[i];
                pA1 += lrelu(xsA[i + 4] + xrv[i + 4]) * atv[i + 4];
                pB0 += lrelu(xsB[i] + xrv[i]) * atv[i];
                pB1 += lrelu(xsB[i + 4] + xrv[i + 4]) * atv[i + 4];
            }
            float pA = red8_dpp(pA0 + pA1);
            float pB = red8_dpp(pB0 + pB1);
            if (base + ej >= dcnt)     pA = -1e30f;
            if (base + 8 + ej >= dcnt) pB = -1e30f;
            float wA = __expf(fminf(pA, 60.f));
            float wB = __expf(fminf(pB, 60.f));
            l += wA + wB;
#pragma unroll
            for (int i = 0; i < 8; ++i) acc8[i] += wA * xsA[i] + wB * xsB[i];
        }
        // reduce over the 8 edge slots: DPP ror8 + swizzle xor16/32
        l = ror8_add(l); l += __shfl_xor(l, 16); l += __shfl_xor(l, 32);
#pragma unroll
        for (int i = 0; i < 8; ++i) {
            acc8[i] = ror8_add(acc8[i]);
            acc8[i] += __shfl_xor(acc8[i], 16);
            acc8[i] += __shfl_xor(acc8[i], 32);
        }
        float inv = 1.f / (l + 1e-16f);
        float v8[8];
        {
            const float* brow = b1 + h * 64 + cg * 8;
#pragma unroll
            for (int i = 0; i < 8; ++i) {
                float v = acc8[i] * inv + brow[i];
                v8[i] = (v > 0.f) ? v : (__expf(v) - 1.f);   // elu (fast exp)
            }
        }
        if (ej == 0) {
            float4 va = {v8[0], v8[1], v8[2], v8[3]};
            float4 vb = {v8[4], v8[5], v8[6], v8[7]};
            float* dst = h1 + (size_t)n * 512 + h * 64 + cg * 8;
            *reinterpret_cast<float4*>(dst)     = va;
            *reinterpret_cast<float4*>(dst + 4) = vb;
        }
    }
}

// ---------------- layer 2 ----------------

// 32 rows x 64 cols per block, 256 thr = 4 waves; wave owns 8 rows.
__global__ __launch_bounds__(256) void k_gemm2(const float* __restrict__ h1,
        const float* __restrict__ Wl, const float* __restrict__ Wr,
        float* __restrict__ xw2) {
    __shared__ float hs[32 * 512];       // 64 KB
    int t = threadIdx.x;
    int wave = t >> 6, j = t & 63;
    int n0 = blockIdx.x * 32;
    {
        float4* hdst = reinterpret_cast<float4*>(hs);
        for (int i = t; i < 32 * 128; i += 256) {
            int rrow = i >> 7;
            int grow = n0 + rrow;
            grow = (grow < N_NODES) ? grow : (N_NODES - 1);
            hdst[i] = reinterpret_cast<const float4*>(
                          h1 + (size_t)grow * 512)[i & 127];
        }
    }
    __syncthreads();
    const float* W = (j < 32) ? (Wl + j) : (Wr + (j - 32));
    float acc[8];
#pragma unroll
    for (int r = 0; r < 8; ++r) acc[r] = 0.f;
    for (int k = 0; k < 512; k += 4) {
        float w0 = W[(size_t)(k + 0) * 32];
        float w1 = W[(size_t)(k + 1) * 32];
        float w2 = W[(size_t)(k + 2) * 32];
        float w3 = W[(size_t)(k + 3) * 32];
#pragma unroll
        for (int r = 0; r < 8; ++r) {
            float4 a = *reinterpret_cast<const float4*>(
                &hs[(wave * 8 + r) * 512 + k]);
            acc[r] += a.x * w0 + a.y * w1 + a.z * w2 + a.w * w3;
        }
    }
#pragma unroll
    for (int r = 0; r < 8; ++r) {
        int grow = n0 + wave * 8 + r;
        if (grow < N_NODES) xw2[(size_t)grow * 64 + j] = acc[r];
    }
}

// Fused edge+node layer 2 + log_softmax — wave-independent, wave = 4 nodes.
// Lane (ej,cg): edges base+ej / base+8+ej, channels cg*4..+3.
__global__ __launch_bounds__(256) void k_node2f(const int* __restrict__ offs,
        const int* __restrict__ ssrc, const float* __restrict__ xw2,
        const float* __restrict__ att2, const float* __restrict__ b2,
        float* __restrict__ out) {
    int t = threadIdx.x;
    int wave = t >> 6, lane = t & 63;
    int ej = lane >> 3;
    int cg = lane & 7;
    int q = blockIdx.x * 4 + wave;
#pragma unroll 1
    for (int pp = 0; pp < 4; ++pp) {
        int n = q * 4 + pp;
        if (n >= N_NODES) return;
        int beg = offs[n], dcnt = offs[n + 1] - beg;
        float4 xr = *reinterpret_cast<const float4*>(
                        xw2 + (size_t)n * 64 + 32 + cg * 4);
        float4 at = *reinterpret_cast<const float4*>(att2 + cg * 4);
        float l = 0.f;
        float4 ac = {0.f, 0.f, 0.f, 0.f};
        const int* sp = ssrc + beg;
        const char* xwbase = reinterpret_cast<const char*>(xw2) + cg * 16;
        int iA = (ej < dcnt) ? ej : (dcnt - 1);
        int iB = (8 + ej < dcnt) ? 8 + ej : (dcnt - 1);
        int sA = sp[iA] << 8, sB = sp[iB] << 8;
        for (int base = 0; base < dcnt; base += 16) {
            float4 uA = *reinterpret_cast<const float4*>(xwbase + sA);
            float4 uB = *reinterpret_cast<const float4*>(xwbase + sB);
            int nA = base + 16 + ej; nA = (nA < dcnt) ? nA : (dcnt - 1);
            int nB = base + 24 + ej; nB = (nB < dcnt) ? nB : (dcnt - 1);
            sA = sp[nA] << 8; sB = sp[nB] << 8;
            float pA0 = lrelu(uA.x + xr.x) * at.x + lrelu(uA.z + xr.z) * at.z;
            float pA1 = lrelu(uA.y + xr.y) * at.y + lrelu(uA.w + xr.w) * at.w;
            float pB0 = lrelu(uB.x + xr.x) * at.x + lrelu(uB.z + xr.z) * at.z;
            float pB1 = lrelu(uB.y + xr.y) * at.y + lrelu(uB.w + xr.w) * at.w;
            float pA = red8_dpp(pA0 + pA1);
            float pB = red8_dpp(pB0 + pB1);
            if (base + ej >= dcnt)     pA = -1e30f;
            if (base + 8 + ej >= dcnt) pB = -1e30f;
            float wA = __expf(fminf(pA, 60.f));
            float wB = __expf(fminf(pB, 60.f));
            l += wA + wB;
            ac.x += wA * uA.x + wB * uB.x;
            ac.y += wA * uA.y + wB * uB.y;
            ac.z += wA * uA.z + wB * uB.z;
            ac.w += wA * uA.w + wB * uB.w;
        }
        l = ror8_add(l); l += __shfl_xor(l, 16); l += __shfl_xor(l, 32);
        ac.x = ror8_add(ac.x); ac.x += __shfl_xor(ac.x, 16); ac.x += __shfl_xor(ac.x, 32);
        ac.y = ror8_add(ac.y); ac.y += __shfl_xor(ac.y, 16); ac.y += __shfl_xor(ac.y, 32);
        ac.z = ror8_add(ac.z); ac.z += __shfl_xor(ac.z, 16); ac.z += __shfl_xor(ac.z, 32);
        ac.w = ror8_add(ac.w); ac.w += __shfl_xor(ac.w, 16); ac.w += __shfl_xor(ac.w, 32);
        float inv = 1.f / (l + 1e-16f);
        float4 bb = *reinterpret_cast<const float4*>(b2 + cg * 4);
        float4 v;
        v.x = ac.x * inv + bb.x; v.y = ac.y * inv + bb.y;
        v.z = ac.z * inv + bb.z; v.w = ac.w * inv + bb.w;
        // log_softmax over 32 channels (8-lane DPP; ej groups identical)
        float mx = red8max_dpp(fmaxf(fmaxf(v.x, v.y), fmaxf(v.z, v.w)));
        float se = red8_dpp(__expf(v.x - mx) + __expf(v.y - mx)
                          + __expf(v.z - mx) + __expf(v.w - mx));
        float ls = __logf(se);
        v.x = v.x - mx - ls; v.y = v.y - mx - ls;
        v.z = v.z - mx - ls; v.w = v.w - mx - ls;
        if (ej == 0)
            *reinterpret_cast<float4*>(out + (size_t)n * 32 + cg * 4) = v;
    }
}

// ---------------- launch ----------------

extern "C" void kernel_launch(void* const* d_in, const int* in_sizes, int n_in,
                              void* d_out, int out_size, void* d_ws, size_t ws_size,
                              hipStream_t stream) {
    (void)in_sizes; (void)n_in; (void)out_size; (void)ws_size;
    const float* x    = (const float*)d_in[0];
    const int*   ei   = (const int*)d_in[1];
    const float* W1l  = (const float*)d_in[2];
    const float* W1r  = (const float*)d_in[3];
    const float* att1 = (const float*)d_in[4];
    const float* b1   = (const float*)d_in[5];
    const float* W2l  = (const float*)d_in[6];
    const float* W2r  = (const float*)d_in[7];
    const float* att2 = (const float*)d_in[8];
    const float* b2   = (const float*)d_in[9];
    float* outp = (float*)d_out;

    char* ws = (char*)d_ws;
    size_t o = 0;
    auto alloc = [&](size_t bytes) {
        char* p = ws + o;
        o = (o + bytes + 255) & ~(size_t)255;
        return p;
    };
    unsigned short* xl1b = (unsigned short*)alloc((size_t)N_NODES * 512 * 2);
    float* xr1    = (float*)alloc((size_t)N_NODES * 512 * 4);
    float* h1     = (float*)alloc((size_t)N_NODES * 512 * 4);
    float* xw2    = (float*)alloc((size_t)N_NODES * 64 * 4);
    unsigned short* Abf = (unsigned short*)alloc((size_t)N_NODES * 768 * 2);
    unsigned short* Bbf = (unsigned short*)alloc((size_t)1024 * 768 * 2);
    int*   deg    = (int*)alloc((size_t)N_NODES * 4);
    int*   offs   = (int*)alloc((size_t)(N_NODES + 1) * 4);
    int*   ssrc   = (int*)alloc((size_t)ET * 4);

    hipMemsetAsync(deg, 0, (size_t)N_NODES * 4, stream);

    k_prep   <<<NB_COUNT + NB_CONVX + NB_CONVW, 256, 0, stream>>>(
                 ei, deg, x, Abf, W1l, W1r, Bbf);
    k_scan   <<<1,                    1024, 0, stream>>>(deg, offs);
    k_scatter<<<(ET + 255) / 256,      256, 0, stream>>>(ei, offs, deg, ssrc);
    k_mfma1  <<<dim3(79, 8),           256, 0, stream>>>(Abf, Bbf, xl1b, xr1);
    k_node1f <<<5000,                  256, 0, stream>>>(offs, ssrc, xl1b, xr1, att1, b1, h1);
    k_gemm2  <<<(N_NODES + 31) / 32,   256, 0, stream>>>(h1, W2l, W2r, xw2);
    k_node2f <<<625,                   256, 0, stream>>>(offs, ssrc, xw2, att2, b2, outp);
}

// Round 16
// 274.386 us; speedup vs baseline: 1.0929x; 1.0929x over previous
//
#include <hip/hip_runtime.h>
#include <hip/hip_bf16.h>

// GATv2 x2 on MI355X — MFMA gemm1 (split-bf16), bf16 xl1 gather, DPP reduce.
// R16 = R14 structure (block=node, wave=head, 80k waves, C=16) MINUS the LDS
// ssrc staging and barriers (R15 insight: each chunk's 16 indices are one
// L1-hot 64B line; staging bought nothing). R15's wave-count cut (20k long
// serial waves) regressed — TLP was the latency hider. Blocks are now
// barrier-free wave containers.

constexpr int N_NODES = 10000;
constexpr int N_EDGES = 320000;
constexpr int ET      = N_EDGES + N_NODES;   // 330000 incl. self loops
constexpr float NEG_SLOPE = 0.2f;

constexpr int NB_COUNT = (ET + 255) / 256;          // 1290
constexpr int NB_CONVX = (N_NODES * 64) / 256;      // 2500
constexpr int NB_CONVW = (1024 * 64) / 256;         // 256

typedef __attribute__((ext_vector_type(8))) short short8;
typedef __attribute__((ext_vector_type(8))) unsigned short ushort8_t;
typedef __attribute__((ext_vector_type(4))) float floatx4;

__device__ __forceinline__ float lrelu(float a) {
    return fmaxf(a, NEG_SLOPE * a);
}
__device__ __forceinline__ unsigned short f2bf(float f) {   // RNE
    unsigned u = __float_as_uint(f);
    unsigned r = u + 0x7FFFu + ((u >> 16) & 1u);
    return (unsigned short)(r >> 16);
}
__device__ __forceinline__ float bf2f(unsigned short h) {
    return __uint_as_float((unsigned)h << 16);
}
// sum over each aligned group of 8 lanes, result in all 8 (pure VALU)
__device__ __forceinline__ float red8_dpp(float p) {
    int x;
    x = __builtin_amdgcn_update_dpp(0, __float_as_int(p), 0xB1, 0xF, 0xF, true);
    p += __int_as_float(x);                  // quad_perm [1,0,3,2]
    x = __builtin_amdgcn_update_dpp(0, __float_as_int(p), 0x4E, 0xF, 0xF, true);
    p += __int_as_float(x);                  // quad_perm [2,3,0,1]
    x = __builtin_amdgcn_update_dpp(0, __float_as_int(p), 0x141, 0xF, 0xF, true);
    p += __int_as_float(x);                  // row_half_mirror
    return p;
}
__device__ __forceinline__ float red8max_dpp(float p) {
    int x;
    x = __builtin_amdgcn_update_dpp(0, __float_as_int(p), 0xB1, 0xF, 0xF, true);
    p = fmaxf(p, __int_as_float(x));
    x = __builtin_amdgcn_update_dpp(0, __float_as_int(p), 0x4E, 0xF, 0xF, true);
    p = fmaxf(p, __int_as_float(x));
    x = __builtin_amdgcn_update_dpp(0, __float_as_int(p), 0x141, 0xF, 0xF, true);
    p = fmaxf(p, __int_as_float(x));
    return p;
}
// pairwise add with lane^8 partner (row_ror:8 within 16-lane rows)
__device__ __forceinline__ float ror8_add(float p) {
    int x = __builtin_amdgcn_update_dpp(0, __float_as_int(p), 0x128, 0xF, 0xF, true);
    return p + __int_as_float(x);
}

// ---------------- fused prep: deg count + conv_x + conv_w ----------------

__global__ __launch_bounds__(256) void k_prep(const int* __restrict__ ei,
        int* __restrict__ deg, const float* __restrict__ x,
        unsigned short* __restrict__ A, const float* __restrict__ Wl,
        const float* __restrict__ Wr, unsigned short* __restrict__ Bt) {
    int b = blockIdx.x, t = threadIdx.x;
    if (b < NB_COUNT) {
        int e = b * 256 + t;
        if (e >= ET) return;
        int d = (e < N_EDGES) ? ei[N_EDGES + e] : (e - N_EDGES);
        atomicAdd(&deg[d], 1);
    } else if (b < NB_COUNT + NB_CONVX) {
        int idx = (b - NB_COUNT) * 256 + t;       // < N_NODES*64
        int m = idx >> 6, kg = (idx & 63) << 2;
        float4 v = *reinterpret_cast<const float4*>(x + (size_t)m * 256 + kg);
        ushort4 hi = make_ushort4(f2bf(v.x), f2bf(v.y), f2bf(v.z), f2bf(v.w));
        ushort4 lo = make_ushort4(f2bf(v.x - bf2f(hi.x)), f2bf(v.y - bf2f(hi.y)),
                                  f2bf(v.z - bf2f(hi.z)), f2bf(v.w - bf2f(hi.w)));
        size_t base = (size_t)m * 768 + kg;
        *reinterpret_cast<ushort4*>(A + base)       = hi;
        *reinterpret_cast<ushort4*>(A + base + 256) = lo;
        *reinterpret_cast<ushort4*>(A + base + 512) = hi;
    } else {
        int idx = (b - NB_COUNT - NB_CONVX) * 256 + t;   // < 1024*64
        int n = idx >> 6, kg = (idx & 63) << 2;
        const float* src = (n < 512) ? (Wl + n) : (Wr + (n - 512));
        float v0 = src[(size_t)(kg + 0) * 512];
        float v1 = src[(size_t)(kg + 1) * 512];
        float v2 = src[(size_t)(kg + 2) * 512];
        float v3 = src[(size_t)(kg + 3) * 512];
        ushort4 hi = make_ushort4(f2bf(v0), f2bf(v1), f2bf(v2), f2bf(v3));
        ushort4 lo = make_ushort4(f2bf(v0 - bf2f(hi.x)), f2bf(v1 - bf2f(hi.y)),
                                  f2bf(v2 - bf2f(hi.z)), f2bf(v3 - bf2f(hi.w)));
        size_t base = (size_t)n * 768 + kg;
        *reinterpret_cast<ushort4*>(Bt + base)       = hi;
        *reinterpret_cast<ushort4*>(Bt + base + 256) = hi;
        *reinterpret_cast<ushort4*>(Bt + base + 512) = lo;
    }
}

// ---------------- CSR scan + scatter ----------------

__global__ __launch_bounds__(1024) void k_scan(const int* __restrict__ deg,
                                               int* __restrict__ offs) {
    __shared__ int part[1024];
    const int CH = 10;                       // ceil(10000/1024)
    int t = threadIdx.x;
    int base = t * CH;
    int loc[CH];
    int s = 0;
    for (int i = 0; i < CH; ++i) {
        int idx = base + i;
        int v = (idx < N_NODES) ? deg[idx] : 0;
        loc[i] = s; s += v;
    }
    part[t] = s;
    __syncthreads();
    for (int o = 1; o < 1024; o <<= 1) {
        int add = (t >= o) ? part[t - o] : 0;
        __syncthreads();
        part[t] += add;
        __syncthreads();
    }
    int excl = part[t] - s;
    for (int i = 0; i < CH; ++i) {
        int idx = base + i;
        if (idx < N_NODES) offs[idx] = excl + loc[i];
    }
    if (t == 1023) offs[N_NODES] = part[1023];
}

// deg doubles as countdown cursor: pos = offs[d] + (--deg[d])
__global__ void k_scatter(const int* __restrict__ ei, const int* __restrict__ offs,
                          int* __restrict__ deg, int* __restrict__ ssrc) {
    int e = blockIdx.x * 256 + threadIdx.x;
    if (e >= ET) return;
    int s, d;
    if (e < N_EDGES) { s = ei[e]; d = ei[N_EDGES + e]; }
    else             { s = d = e - N_EDGES; }
    int pos = offs[d] + atomicAdd(&deg[d], -1) - 1;
    ssrc[pos] = s;
}

// ---------------- layer 1 MFMA GEMM ----------------

// 128x128 tile, M=10000 N=1024 K=768, grid (79,8), 4 waves/block.
__global__ __launch_bounds__(256) void k_mfma1(const unsigned short* __restrict__ A,
        const unsigned short* __restrict__ Bt, unsigned short* __restrict__ xl1b,
        float* __restrict__ xr1) {
    __shared__ unsigned short As[128 * 40];   // stride 40: 2-way max = free
    __shared__ unsigned short Bs[128 * 40];
    int t = threadIdx.x;
    int wave = t >> 6, L = t & 63;
    int wm = wave & 1, wn = wave >> 1;
    int row0 = blockIdx.x * 128, n0 = blockIdx.y * 128;
    int q = L >> 4, rr = L & 15;
    floatx4 acc[4][4];
#pragma unroll
    for (int i = 0; i < 4; ++i)
#pragma unroll
        for (int j = 0; j < 4; ++j) acc[i][j] = (floatx4){0.f, 0.f, 0.f, 0.f};
    int ra = t >> 2,        ka = (t & 3) * 8;
    int rb = (t + 256) >> 2, kb = ((t + 256) & 3) * 8;
    int gma = row0 + ra; gma = (gma < N_NODES) ? gma : (N_NODES - 1);
    int gmb = row0 + rb; gmb = (gmb < N_NODES) ? gmb : (N_NODES - 1);
    for (int kc = 0; kc < 768; kc += 32) {
        __syncthreads();
        *reinterpret_cast<uint4*>(&As[ra * 40 + ka]) =
            *reinterpret_cast<const uint4*>(A + (size_t)gma * 768 + kc + ka);
        *reinterpret_cast<uint4*>(&As[rb * 40 + kb]) =
            *reinterpret_cast<const uint4*>(A + (size_t)gmb * 768 + kc + kb);
        *reinterpret_cast<uint4*>(&Bs[ra * 40 + ka]) =
            *reinterpret_cast<const uint4*>(Bt + (size_t)(n0 + ra) * 768 + kc + ka);
        *reinterpret_cast<uint4*>(&Bs[rb * 40 + kb]) =
            *reinterpret_cast<const uint4*>(Bt + (size_t)(n0 + rb) * 768 + kc + kb);
        __syncthreads();
        short8 af[4], bf[4];
#pragma unroll
        for (int st = 0; st < 4; ++st)
            af[st] = *reinterpret_cast<const short8*>(
                &As[(wm * 64 + st * 16 + rr) * 40 + q * 8]);
#pragma unroll
        for (int st = 0; st < 4; ++st)
            bf[st] = *reinterpret_cast<const short8*>(
                &Bs[(wn * 64 + st * 16 + rr) * 40 + q * 8]);
#pragma unroll
        for (int i = 0; i < 4; ++i)
#pragma unroll
            for (int j = 0; j < 4; ++j)
                acc[i][j] = __builtin_amdgcn_mfma_f32_16x16x32_bf16(
                    af[i], bf[j], acc[i][j], 0, 0, 0);
    }
    // epilogue: C/D layout col=lane&15, row=(lane>>4)*4+reg  [m89/m91]
#pragma unroll
    for (int j = 0; j < 4; ++j) {
        int gc = n0 + wn * 64 + j * 16 + rr;
        if (gc < 512) {
#pragma unroll
            for (int i = 0; i < 4; ++i)
#pragma unroll
                for (int r = 0; r < 4; ++r) {
                    int gr = row0 + wm * 64 + i * 16 + q * 4 + r;
                    if (gr < N_NODES)
                        xl1b[(size_t)gr * 512 + gc] = f2bf(acc[i][j][r]);
                }
        } else {
            int col = gc - 512;
#pragma unroll
            for (int i = 0; i < 4; ++i)
#pragma unroll
                for (int r = 0; r < 4; ++r) {
                    int gr = row0 + wm * 64 + i * 16 + q * 4 + r;
                    if (gr < N_NODES)
                        xr1[(size_t)gr * 512 + col] = acc[i][j][r];
                }
        }
    }
}

// Fused edge+node layer 1: block = node (512 thr = 8 waves, wave = head),
// NO LDS / NO barriers — ssrc read directly (L1-hot 64B line per chunk,
// shared across the node's 8 head-waves). C=16, DPP reduce, fast elu.
__global__ __launch_bounds__(512) void k_node1f(const int* __restrict__ offs,
        const int* __restrict__ ssrc, const unsigned short* __restrict__ xl1b,
        const float* __restrict__ xr1, const float* __restrict__ att1,
        const float* __restrict__ b1, float* __restrict__ h1) {
    int n = blockIdx.x;
    int t = threadIdx.x;
    int h = t >> 6, lane = t & 63;
    int beg = offs[n], dcnt = offs[n + 1] - beg;
    int ej = lane >> 3;                  // edge slot
    int cg = lane & 7;                   // channel group of 8
    float xrv[8], atv[8];
    {
        const float* xrrow = xr1 + (size_t)n * 512 + h * 64 + cg * 8;
        const float* atrow = att1 + h * 64 + cg * 8;
        float4 a0 = *reinterpret_cast<const float4*>(xrrow);
        float4 a1 = *reinterpret_cast<const float4*>(xrrow + 4);
        float4 c0 = *reinterpret_cast<const float4*>(atrow);
        float4 c1 = *reinterpret_cast<const float4*>(atrow + 4);
        xrv[0]=a0.x; xrv[1]=a0.y; xrv[2]=a0.z; xrv[3]=a0.w;
        xrv[4]=a1.x; xrv[5]=a1.y; xrv[6]=a1.z; xrv[7]=a1.w;
        atv[0]=c0.x; atv[1]=c0.y; atv[2]=c0.z; atv[3]=c0.w;
        atv[4]=c1.x; atv[5]=c1.y; atv[6]=c1.z; atv[7]=c1.w;
    }
    float l = 0.f;
    float acc8[8];
#pragma unroll
    for (int i = 0; i < 8; ++i) acc8[i] = 0.f;
    const int* sp = ssrc + beg;
    const char* xlbase = reinterpret_cast<const char*>(xl1b) + h * 128 + cg * 16;

    auto ld_off = [&](int i1) -> int {
        int i1c = (i1 < dcnt) ? i1 : (dcnt - 1);   // dcnt >= 1 (self loop)
        return sp[i1c] << 10;
    };
    auto ld_row = [&](int off) -> ushort8_t {
        return *reinterpret_cast<const ushort8_t*>(xlbase + off);
    };
    ushort8_t uA = ld_row(ld_off(ej));
    ushort8_t uB = ld_row(ld_off(8 + ej));
    int oA1 = ld_off(16 + ej), oB1 = ld_off(24 + ej);
    for (int base = 0; base < dcnt; base += 16) {
        ushort8_t uA1 = ld_row(oA1), uB1 = ld_row(oB1);   // rows +1 chunk
        int oA2 = ld_off(base + 32 + ej);                 // offs +2 chunks
        int oB2 = ld_off(base + 40 + ej);
        float xsA[8], xsB[8];
#pragma unroll
        for (int i = 0; i < 8; ++i) { xsA[i] = bf2f(uA[i]); xsB[i] = bf2f(uB[i]); }
        float pA0 = 0.f, pA1 = 0.f, pB0 = 0.f, pB1 = 0.f;
#pragma unroll
        for (int i = 0; i < 4; ++i) {
            pA0 += lrelu(xsA[i] + xrv[i]) * atv[i];
            pA1 += lrelu(xsA[i + 4] + xrv[i + 4]) * atv[i + 4];
            pB0 += lrelu(xsB[i] + xrv[i]) * atv[i];
            pB1 += lrelu(xsB[i + 4] + xrv[i + 4]) * atv[i + 4];
        }
        float pA = red8_dpp(pA0 + pA1);
        float pB = red8_dpp(pB0 + pB1);
        if (base + ej >= dcnt)     pA = -1e30f;
        if (base + 8 + ej >= dcnt) pB = -1e30f;
        float wA = __expf(fminf(pA, 60.f));
        float wB = __expf(fminf(pB, 60.f));
        l += wA + wB;
#pragma unroll
        for (int i = 0; i < 8; ++i) acc8[i] += wA * xsA[i] + wB * xsB[i];
        uA = uA1; uB = uB1; oA1 = oA2; oB1 = oB2;
    }
    // reduce over the 8 edge slots: DPP ror8 + swizzle xor16/32
    l = ror8_add(l); l += __shfl_xor(l, 16); l += __shfl_xor(l, 32);
#pragma unroll
    for (int i = 0; i < 8; ++i) {
        acc8[i] = ror8_add(acc8[i]);
        acc8[i] += __shfl_xor(acc8[i], 16);
        acc8[i] += __shfl_xor(acc8[i], 32);
    }
    float inv = 1.f / (l + 1e-16f);
    float v8[8];
    {
        const float* brow = b1 + h * 64 + cg * 8;
#pragma unroll
        for (int i = 0; i < 8; ++i) {
            float v = acc8[i] * inv + brow[i];
            v8[i] = (v > 0.f) ? v : (__expf(v) - 1.f);   // elu (fast exp)
        }
    }
    if (ej == 0) {
        float4 va = {v8[0], v8[1], v8[2], v8[3]};
        float4 vb = {v8[4], v8[5], v8[6], v8[7]};
        float* dst = h1 + (size_t)n * 512 + h * 64 + cg * 8;
        *reinterpret_cast<float4*>(dst)     = va;
        *reinterpret_cast<float4*>(dst + 4) = vb;
    }
}

// ---------------- layer 2 ----------------

// 32 rows x 64 cols per block, 256 thr = 4 waves; wave owns 8 rows.
__global__ __launch_bounds__(256) void k_gemm2(const float* __restrict__ h1,
        const float* __restrict__ Wl, const float* __restrict__ Wr,
        float* __restrict__ xw2) {
    __shared__ float hs[32 * 512];       // 64 KB
    int t = threadIdx.x;
    int wave = t >> 6, j = t & 63;
    int n0 = blockIdx.x * 32;
    {
        float4* hdst = reinterpret_cast<float4*>(hs);
        for (int i = t; i < 32 * 128; i += 256) {
            int rrow = i >> 7;
            int grow = n0 + rrow;
            grow = (grow < N_NODES) ? grow : (N_NODES - 1);
            hdst[i] = reinterpret_cast<const float4*>(
                          h1 + (size_t)grow * 512)[i & 127];
        }
    }
    __syncthreads();
    const float* W = (j < 32) ? (Wl + j) : (Wr + (j - 32));
    float acc[8];
#pragma unroll
    for (int r = 0; r < 8; ++r) acc[r] = 0.f;
    for (int k = 0; k < 512; k += 4) {
        float w0 = W[(size_t)(k + 0) * 32];
        float w1 = W[(size_t)(k + 1) * 32];
        float w2 = W[(size_t)(k + 2) * 32];
        float w3 = W[(size_t)(k + 3) * 32];
#pragma unroll
        for (int r = 0; r < 8; ++r) {
            float4 a = *reinterpret_cast<const float4*>(
                &hs[(wave * 8 + r) * 512 + k]);
            acc[r] += a.x * w0 + a.y * w1 + a.z * w2 + a.w * w3;
        }
    }
#pragma unroll
    for (int r = 0; r < 8; ++r) {
        int grow = n0 + wave * 8 + r;
        if (grow < N_NODES) xw2[(size_t)grow * 64 + j] = acc[r];
    }
}

// Fused edge+node layer 2 + log_softmax: block = 4 nodes, wave = node,
// NO LDS / NO barriers; ssrc direct. Lane (ej,cg): edges base+ej/base+8+ej.
__global__ __launch_bounds__(256) void k_node2f(const int* __restrict__ offs,
        const int* __restrict__ ssrc, const float* __restrict__ xw2,
        const float* __restrict__ att2, const float* __restrict__ b2,
        float* __restrict__ out) {
    int t = threadIdx.x;
    int wave = t >> 6, lane = t & 63;
    int n = blockIdx.x * 4 + wave;
    if (n >= N_NODES) return;
    int ej = lane >> 3;
    int cg = lane & 7;
    int beg = offs[n], dcnt = offs[n + 1] - beg;
    float4 xr = *reinterpret_cast<const float4*>(
                    xw2 + (size_t)n * 64 + 32 + cg * 4);
    float4 at = *reinterpret_cast<const float4*>(att2 + cg * 4);
    float l = 0.f;
    float4 ac = {0.f, 0.f, 0.f, 0.f};
    const int* sp = ssrc + beg;
    const char* xwbase = reinterpret_cast<const char*>(xw2) + cg * 16;
    auto ld_off = [&](int i1) -> int {
        int i1c = (i1 < dcnt) ? i1 : (dcnt - 1);
        return sp[i1c] << 8;
    };
    auto ld_row = [&](int off) -> float4 {
        return *reinterpret_cast<const float4*>(xwbase + off);
    };
    float4 uA = ld_row(ld_off(ej));
    float4 uB = ld_row(ld_off(8 + ej));
    int oA1 = ld_off(16 + ej), oB1 = ld_off(24 + ej);
    for (int base = 0; base < dcnt; base += 16) {
        float4 uA1 = ld_row(oA1), uB1 = ld_row(oB1);
        int oA2 = ld_off(base + 32 + ej);
        int oB2 = ld_off(base + 40 + ej);
        float pA0 = lrelu(uA.x + xr.x) * at.x + lrelu(uA.z + xr.z) * at.z;
        float pA1 = lrelu(uA.y + xr.y) * at.y + lrelu(uA.w + xr.w) * at.w;
        float pB0 = lrelu(uB.x + xr.x) * at.x + lrelu(uB.z + xr.z) * at.z;
        float pB1 = lrelu(uB.y + xr.y) * at.y + lrelu(uB.w + xr.w) * at.w;
        float pA = red8_dpp(pA0 + pA1);
        float pB = red8_dpp(pB0 + pB1);
        if (base + ej >= dcnt)     pA = -1e30f;
        if (base + 8 + ej >= dcnt) pB = -1e30f;
        float wA = __expf(fminf(pA, 60.f));
        float wB = __expf(fminf(pB, 60.f));
        l += wA + wB;
        ac.x += wA * uA.x + wB * uB.x;
        ac.y += wA * uA.y + wB * uB.y;
        ac.z += wA * uA.z + wB * uB.z;
        ac.w += wA * uA.w + wB * uB.w;
        uA = uA1; uB = uB1; oA1 = oA2; oB1 = oB2;
    }
    l = ror8_add(l); l += __shfl_xor(l, 16); l += __shfl_xor(l, 32);
    ac.x = ror8_add(ac.x); ac.x += __shfl_xor(ac.x, 16); ac.x += __shfl_xor(ac.x, 32);
    ac.y = ror8_add(ac.y); ac.y += __shfl_xor(ac.y, 16); ac.y += __shfl_xor(ac.y, 32);
    ac.z = ror8_add(ac.z); ac.z += __shfl_xor(ac.z, 16); ac.z += __shfl_xor(ac.z, 32);
    ac.w = ror8_add(ac.w); ac.w += __shfl_xor(ac.w, 16); ac.w += __shfl_xor(ac.w, 32);
    float inv = 1.f / (l + 1e-16f);
    float4 bb = *reinterpret_cast<const float4*>(b2 + cg * 4);
    float4 v;
    v.x = ac.x * inv + bb.x; v.y = ac.y * inv + bb.y;
    v.z = ac.z * inv + bb.z; v.w = ac.w * inv + bb.w;
    // log_softmax over 32 channels (8-lane DPP; ej groups identical)
    float mx = red8max_dpp(fmaxf(fmaxf(v.x, v.y), fmaxf(v.z, v.w)));
    float se = red8_dpp(__expf(v.x - mx) + __expf(v.y - mx)
                      + __expf(v.z - mx) + __expf(v.w - mx));
    float ls = __logf(se);
    v.x = v.x - mx - ls; v.y = v.y - mx - ls;
    v.z = v.z - mx - ls; v.w = v.w - mx - ls;
    if (ej == 0)
        *reinterpret_cast<float4*>(out + (size_t)n * 32 + cg * 4) = v;
}

// ---------------- launch ----------------

extern "C" void kernel_launch(void* const* d_in, const int* in_sizes, int n_in,
                              void* d_out, int out_size, void* d_ws, size_t ws_size,
                              hipStream_t stream) {
    (void)in_sizes; (void)n_in; (void)out_size; (void)ws_size;
    const float* x    = (const float*)d_in[0];
    const int*   ei   = (const int*)d_in[1];
    const float* W1l  = (const float*)d_in[2];
    const float* W1r  = (const float*)d_in[3];
    const float* att1 = (const float*)d_in[4];
    const float* b1   = (const float*)d_in[5];
    const float* W2l  = (const float*)d_in[6];
    const float* W2r  = (const float*)d_in[7];
    const float* att2 = (const float*)d_in[8];
    const float* b2   = (const float*)d_in[9];
    float* outp = (float*)d_out;

    char* ws = (char*)d_ws;
    size_t o = 0;
    auto alloc = [&](size_t bytes) {
        char* p = ws + o;
        o = (o + bytes + 255) & ~(size_t)255;
        return p;
    };
    unsigned short* xl1b = (unsigned short*)alloc((size_t)N_NODES * 512 * 2);
    float* xr1    = (float*)alloc((size_t)N_NODES * 512 * 4);
    float* h1     = (float*)alloc((size_t)N_NODES * 512 * 4);
    float* xw2    = (float*)alloc((size_t)N_NODES * 64 * 4);
    unsigned short* Abf = (unsigned short*)alloc((size_t)N_NODES * 768 * 2);
    unsigned short* Bbf = (unsigned short*)alloc((size_t)1024 * 768 * 2);
    int*   deg    = (int*)alloc((size_t)N_NODES * 4);
    int*   offs   = (int*)alloc((size_t)(N_NODES + 1) * 4);
    int*   ssrc   = (int*)alloc((size_t)ET * 4);

    hipMemsetAsync(deg, 0, (size_t)N_NODES * 4, stream);

    k_prep   <<<NB_COUNT + NB_CONVX + NB_CONVW, 256, 0, stream>>>(
                 ei, deg, x, Abf, W1l, W1r, Bbf);
    k_scan   <<<1,                    1024, 0, stream>>>(deg, offs);
    k_scatter<<<(ET + 255) / 256,      256, 0, stream>>>(ei, offs, deg, ssrc);
    k_mfma1  <<<dim3(79, 8),           256, 0, stream>>>(Abf, Bbf, xl1b, xr1);
    k_node1f <<<N_NODES,               512, 0, stream>>>(offs, ssrc, xl1b, xr1, att1, b1, h1);
    k_gemm2  <<<(N_NODES + 31) / 32,   256, 0, stream>>>(h1, W2l, W2r, xw2);
    k_node2f <<<(N_NODES + 3) / 4,     256, 0, stream>>>(offs, ssrc, xw2, att2, b2, outp);
}

// Round 18
// 257.966 us; speedup vs baseline: 1.1625x; 1.0637x over previous
//
#include <hip/hip_runtime.h>
#include <hip/hip_bf16.h>

// GATv2 x2 on MI355X — R17 (resubmit; R17 bench was a broker timeout, no data).
//  - mfma1 K'=512: A'=[Ah|Al], B'=[Bh;Bh] -> (Ah+Al)*Bh_bf16. Dropped Ah*Bl
//    term is ~2e-3 abs — same scale as bf16-rounding xl1 (R10: absmax
//    bit-identical). 16 K-iters instead of 24.
//  - node kernels: full-chunk hot loop (no masks, no dup loads) + one masked
//    tail iteration. Barrier-free R16 structure kept (block=node, wave=head).
//  - gemm2: 16 rows/block (32 KB LDS) -> 5 blocks/CU.

constexpr int N_NODES = 10000;
constexpr int N_EDGES = 320000;
constexpr int ET      = N_EDGES + N_NODES;   // 330000 incl. self loops
constexpr float NEG_SLOPE = 0.2f;

constexpr int NB_COUNT = (ET + 255) / 256;          // 1290
constexpr int NB_CONVX = (N_NODES * 64) / 256;      // 2500
constexpr int NB_CONVW = (1024 * 64) / 256;         // 256

typedef __attribute__((ext_vector_type(8))) short short8;
typedef __attribute__((ext_vector_type(8))) unsigned short ushort8_t;
typedef __attribute__((ext_vector_type(4))) float floatx4;

__device__ __forceinline__ float lrelu(float a) {
    return fmaxf(a, NEG_SLOPE * a);
}
__device__ __forceinline__ unsigned short f2bf(float f) {   // RNE
    unsigned u = __float_as_uint(f);
    unsigned r = u + 0x7FFFu + ((u >> 16) & 1u);
    return (unsigned short)(r >> 16);
}
__device__ __forceinline__ float bf2f(unsigned short h) {
    return __uint_as_float((unsigned)h << 16);
}
// sum over each aligned group of 8 lanes, result in all 8 (pure VALU)
__device__ __forceinline__ float red8_dpp(float p) {
    int x;
    x = __builtin_amdgcn_update_dpp(0, __float_as_int(p), 0xB1, 0xF, 0xF, true);
    p += __int_as_float(x);                  // quad_perm [1,0,3,2]
    x = __builtin_amdgcn_update_dpp(0, __float_as_int(p), 0x4E, 0xF, 0xF, true);
    p += __int_as_float(x);                  // quad_perm [2,3,0,1]
    x = __builtin_amdgcn_update_dpp(0, __float_as_int(p), 0x141, 0xF, 0xF, true);
    p += __int_as_float(x);                  // row_half_mirror
    return p;
}
__device__ __forceinline__ float red8max_dpp(float p) {
    int x;
    x = __builtin_amdgcn_update_dpp(0, __float_as_int(p), 0xB1, 0xF, 0xF, true);
    p = fmaxf(p, __int_as_float(x));
    x = __builtin_amdgcn_update_dpp(0, __float_as_int(p), 0x4E, 0xF, 0xF, true);
    p = fmaxf(p, __int_as_float(x));
    x = __builtin_amdgcn_update_dpp(0, __float_as_int(p), 0x141, 0xF, 0xF, true);
    p = fmaxf(p, __int_as_float(x));
    return p;
}
// pairwise add with lane^8 partner (row_ror:8 within 16-lane rows)
__device__ __forceinline__ float ror8_add(float p) {
    int x = __builtin_amdgcn_update_dpp(0, __float_as_int(p), 0x128, 0xF, 0xF, true);
    return p + __int_as_float(x);
}

// ---------------- fused prep: deg count + conv_x + conv_w ----------------

__global__ __launch_bounds__(256) void k_prep(const int* __restrict__ ei,
        int* __restrict__ deg, const float* __restrict__ x,
        unsigned short* __restrict__ A, const float* __restrict__ Wl,
        const float* __restrict__ Wr, unsigned short* __restrict__ Bt) {
    int b = blockIdx.x, t = threadIdx.x;
    if (b < NB_COUNT) {
        int e = b * 256 + t;
        if (e >= ET) return;
        int d = (e < N_EDGES) ? ei[N_EDGES + e] : (e - N_EDGES);
        atomicAdd(&deg[d], 1);
    } else if (b < NB_COUNT + NB_CONVX) {
        int idx = (b - NB_COUNT) * 256 + t;       // < N_NODES*64
        int m = idx >> 6, kg = (idx & 63) << 2;
        float4 v = *reinterpret_cast<const float4*>(x + (size_t)m * 256 + kg);
        ushort4 hi = make_ushort4(f2bf(v.x), f2bf(v.y), f2bf(v.z), f2bf(v.w));
        ushort4 lo = make_ushort4(f2bf(v.x - bf2f(hi.x)), f2bf(v.y - bf2f(hi.y)),
                                  f2bf(v.z - bf2f(hi.z)), f2bf(v.w - bf2f(hi.w)));
        size_t base = (size_t)m * 512 + kg;
        *reinterpret_cast<ushort4*>(A + base)       = hi;
        *reinterpret_cast<ushort4*>(A + base + 256) = lo;
    } else {
        int idx = (b - NB_COUNT - NB_CONVX) * 256 + t;   // < 1024*64
        int n = idx >> 6, kg = (idx & 63) << 2;
        const float* src = (n < 512) ? (Wl + n) : (Wr + (n - 512));
        float v0 = src[(size_t)(kg + 0) * 512];
        float v1 = src[(size_t)(kg + 1) * 512];
        float v2 = src[(size_t)(kg + 2) * 512];
        float v3 = src[(size_t)(kg + 3) * 512];
        ushort4 hi = make_ushort4(f2bf(v0), f2bf(v1), f2bf(v2), f2bf(v3));
        size_t base = (size_t)n * 512 + kg;
        *reinterpret_cast<ushort4*>(Bt + base)       = hi;
        *reinterpret_cast<ushort4*>(Bt + base + 256) = hi;   // duplicated seg
    }
}

// ---------------- CSR scan + scatter ----------------

__global__ __launch_bounds__(1024) void k_scan(const int* __restrict__ deg,
                                               int* __restrict__ offs) {
    __shared__ int part[1024];
    const int CH = 10;                       // ceil(10000/1024)
    int t = threadIdx.x;
    int base = t * CH;
    int loc[CH];
    int s = 0;
    for (int i = 0; i < CH; ++i) {
        int idx = base + i;
        int v = (idx < N_NODES) ? deg[idx] : 0;
        loc[i] = s; s += v;
    }
    part[t] = s;
    __syncthreads();
    for (int o = 1; o < 1024; o <<= 1) {
        int add = (t >= o) ? part[t - o] : 0;
        __syncthreads();
        part[t] += add;
        __syncthreads();
    }
    int excl = part[t] - s;
    for (int i = 0; i < CH; ++i) {
        int idx = base + i;
        if (idx < N_NODES) offs[idx] = excl + loc[i];
    }
    if (t == 1023) offs[N_NODES] = part[1023];
}

// deg doubles as countdown cursor: pos = offs[d] + (--deg[d])
__global__ void k_scatter(const int* __restrict__ ei, const int* __restrict__ offs,
                          int* __restrict__ deg, int* __restrict__ ssrc) {
    int e = blockIdx.x * 256 + threadIdx.x;
    if (e >= ET) return;
    int s, d;
    if (e < N_EDGES) { s = ei[e]; d = ei[N_EDGES + e]; }
    else             { s = d = e - N_EDGES; }
    int pos = offs[d] + atomicAdd(&deg[d], -1) - 1;
    ssrc[pos] = s;
}

// ---------------- layer 1 MFMA GEMM ----------------

// 128x128 tile, M=10000 N=1024 K=512, grid (79,8), 4 waves/block.
__global__ __launch_bounds__(256) void k_mfma1(const unsigned short* __restrict__ A,
        const unsigned short* __restrict__ Bt, unsigned short* __restrict__ xl1b,
        float* __restrict__ xr1) {
    __shared__ unsigned short As[128 * 40];   // stride 40: 2-way max = free
    __shared__ unsigned short Bs[128 * 40];
    int t = threadIdx.x;
    int wave = t >> 6, L = t & 63;
    int wm = wave & 1, wn = wave >> 1;
    int row0 = blockIdx.x * 128, n0 = blockIdx.y * 128;
    int q = L >> 4, rr = L & 15;
    floatx4 acc[4][4];
#pragma unroll
    for (int i = 0; i < 4; ++i)
#pragma unroll
        for (int j = 0; j < 4; ++j) acc[i][j] = (floatx4){0.f, 0.f, 0.f, 0.f};
    int ra = t >> 2,        ka = (t & 3) * 8;
    int rb = (t + 256) >> 2, kb = ((t + 256) & 3) * 8;
    int gma = row0 + ra; gma = (gma < N_NODES) ? gma : (N_NODES - 1);
    int gmb = row0 + rb; gmb = (gmb < N_NODES) ? gmb : (N_NODES - 1);
    for (int kc = 0; kc < 512; kc += 32) {
        __syncthreads();
        *reinterpret_cast<uint4*>(&As[ra * 40 + ka]) =
            *reinterpret_cast<const uint4*>(A + (size_t)gma * 512 + kc + ka);
        *reinterpret_cast<uint4*>(&As[rb * 40 + kb]) =
            *reinterpret_cast<const uint4*>(A + (size_t)gmb * 512 + kc + kb);
        *reinterpret_cast<uint4*>(&Bs[ra * 40 + ka]) =
            *reinterpret_cast<const uint4*>(Bt + (size_t)(n0 + ra) * 512 + kc + ka);
        *reinterpret_cast<uint4*>(&Bs[rb * 40 + kb]) =
            *reinterpret_cast<const uint4*>(Bt + (size_t)(n0 + rb) * 512 + kc + kb);
        __syncthreads();
        short8 af[4], bf[4];
#pragma unroll
        for (int st = 0; st < 4; ++st)
            af[st] = *reinterpret_cast<const short8*>(
                &As[(wm * 64 + st * 16 + rr) * 40 + q * 8]);
#pragma unroll
        for (int st = 0; st < 4; ++st)
            bf[st] = *reinterpret_cast<const short8*>(
                &Bs[(wn * 64 + st * 16 + rr) * 40 + q * 8]);
#pragma unroll
        for (int i = 0; i < 4; ++i)
#pragma unroll
            for (int j = 0; j < 4; ++j)
                acc[i][j] = __builtin_amdgcn_mfma_f32_16x16x32_bf16(
                    af[i], bf[j], acc[i][j], 0, 0, 0);
    }
    // epilogue: C/D layout col=lane&15, row=(lane>>4)*4+reg  [m89/m91]
#pragma unroll
    for (int j = 0; j < 4; ++j) {
        int gc = n0 + wn * 64 + j * 16 + rr;
        if (gc < 512) {
#pragma unroll
            for (int i = 0; i < 4; ++i)
#pragma unroll
                for (int r = 0; r < 4; ++r) {
                    int gr = row0 + wm * 64 + i * 16 + q * 4 + r;
                    if (gr < N_NODES)
                        xl1b[(size_t)gr * 512 + gc] = f2bf(acc[i][j][r]);
                }
        } else {
            int col = gc - 512;
#pragma unroll
            for (int i = 0; i < 4; ++i)
#pragma unroll
                for (int r = 0; r < 4; ++r) {
                    int gr = row0 + wm * 64 + i * 16 + q * 4 + r;
                    if (gr < N_NODES)
                        xr1[(size_t)gr * 512 + col] = acc[i][j][r];
                }
        }
    }
}

// Fused edge+node layer 1: block = node (512 thr = 8 waves, wave = head),
// barrier-free. Full-chunk hot loop (no masks) + one masked tail iteration.
__global__ __launch_bounds__(512) void k_node1f(const int* __restrict__ offs,
        const int* __restrict__ ssrc, const unsigned short* __restrict__ xl1b,
        const float* __restrict__ xr1, const float* __restrict__ att1,
        const float* __restrict__ b1, float* __restrict__ h1) {
    int n = blockIdx.x;
    int t = threadIdx.x;
    int h = t >> 6, lane = t & 63;
    int beg = offs[n], dcnt = offs[n + 1] - beg;
    int ej = lane >> 3;                  // edge slot
    int cg = lane & 7;                   // channel group of 8
    float xrv[8], atv[8];
    {
        const float* xrrow = xr1 + (size_t)n * 512 + h * 64 + cg * 8;
        const float* atrow = att1 + h * 64 + cg * 8;
        float4 a0 = *reinterpret_cast<const float4*>(xrrow);
        float4 a1 = *reinterpret_cast<const float4*>(xrrow + 4);
        float4 c0 = *reinterpret_cast<const float4*>(atrow);
        float4 c1 = *reinterpret_cast<const float4*>(atrow + 4);
        xrv[0]=a0.x; xrv[1]=a0.y; xrv[2]=a0.z; xrv[3]=a0.w;
        xrv[4]=a1.x; xrv[5]=a1.y; xrv[6]=a1.z; xrv[7]=a1.w;
        atv[0]=c0.x; atv[1]=c0.y; atv[2]=c0.z; atv[3]=c0.w;
        atv[4]=c1.x; atv[5]=c1.y; atv[6]=c1.z; atv[7]=c1.w;
    }
    float l = 0.f;
    float acc8[8];
#pragma unroll
    for (int i = 0; i < 8; ++i) acc8[i] = 0.f;
    const int* sp = ssrc + beg;
    const char* xlbase = reinterpret_cast<const char*>(xl1b) + h * 128 + cg * 16;

    auto ld_off = [&](int i1) -> int {
        int i1c = (i1 < dcnt) ? i1 : (dcnt - 1);   // dcnt >= 1 (self loop)
        return sp[i1c] << 10;
    };
    auto ld_row = [&](int off) -> ushort8_t {
        return *reinterpret_cast<const ushort8_t*>(xlbase + off);
    };
    int full = dcnt & ~15;               // edges covered by full 16-chunks
    ushort8_t uA = ld_row(ld_off(ej));
    ushort8_t uB = ld_row(ld_off(8 + ej));
    int oA1 = ld_off(16 + ej), oB1 = ld_off(24 + ej);
    for (int base = 0; base < full; base += 16) {
        ushort8_t uA1 = ld_row(oA1), uB1 = ld_row(oB1);   // rows +1 chunk
        int oA2 = ld_off(base + 32 + ej);                 // offs +2 chunks
        int oB2 = ld_off(base + 40 + ej);
        float xsA[8], xsB[8];
#pragma unroll
        for (int i = 0; i < 8; ++i) { xsA[i] = bf2f(uA[i]); xsB[i] = bf2f(uB[i]); }
        float pA0 = 0.f, pA1 = 0.f, pB0 = 0.f, pB1 = 0.f;
#pragma unroll
        for (int i = 0; i < 4; ++i) {
            pA0 += lrelu(xsA[i] + xrv[i]) * atv[i];
            pA1 += lrelu(xsA[i + 4] + xrv[i + 4]) * atv[i + 4];
            pB0 += lrelu(xsB[i] + xrv[i]) * atv[i];
            pB1 += lrelu(xsB[i + 4] + xrv[i + 4]) * atv[i + 4];
        }
        float wA = __expf(fminf(red8_dpp(pA0 + pA1), 60.f));
        float wB = __expf(fminf(red8_dpp(pB0 + pB1), 60.f));
        l += wA + wB;
#pragma unroll
        for (int i = 0; i < 8; ++i) acc8[i] += wA * xsA[i] + wB * xsB[i];
        uA = uA1; uB = uB1; oA1 = oA2; oB1 = oB2;
    }
    if (full < dcnt) {                   // masked tail (single iteration)
        float xsA[8], xsB[8];
#pragma unroll
        for (int i = 0; i < 8; ++i) { xsA[i] = bf2f(uA[i]); xsB[i] = bf2f(uB[i]); }
        float pA0 = 0.f, pA1 = 0.f, pB0 = 0.f, pB1 = 0.f;
#pragma unroll
        for (int i = 0; i < 4; ++i) {
            pA0 += lrelu(xsA[i] + xrv[i]) * atv[i];
            pA1 += lrelu(xsA[i + 4] + xrv[i + 4]) * atv[i + 4];
            pB0 += lrelu(xsB[i] + xrv[i]) * atv[i];
            pB1 += lrelu(xsB[i + 4] + xrv[i + 4]) * atv[i + 4];
        }
        float pA = red8_dpp(pA0 + pA1);
        float pB = red8_dpp(pB0 + pB1);
        if (full + ej >= dcnt)     pA = -1e30f;
        if (full + 8 + ej >= dcnt) pB = -1e30f;
        float wA = __expf(fminf(pA, 60.f));
        float wB = __expf(fminf(pB, 60.f));
        l += wA + wB;
#pragma unroll
        for (int i = 0; i < 8; ++i) acc8[i] += wA * xsA[i] + wB * xsB[i];
    }
    // reduce over the 8 edge slots: DPP ror8 + swizzle xor16/32
    l = ror8_add(l); l += __shfl_xor(l, 16); l += __shfl_xor(l, 32);
#pragma unroll
    for (int i = 0; i < 8; ++i) {
        acc8[i] = ror8_add(acc8[i]);
        acc8[i] += __shfl_xor(acc8[i], 16);
        acc8[i] += __shfl_xor(acc8[i], 32);
    }
    float inv = 1.f / (l + 1e-16f);
    float v8[8];
    {
        const float* brow = b1 + h * 64 + cg * 8;
#pragma unroll
        for (int i = 0; i < 8; ++i) {
            float v = acc8[i] * inv + brow[i];
            v8[i] = (v > 0.f) ? v : (__expf(v) - 1.f);   // elu (fast exp)
        }
    }
    if (ej == 0) {
        float4 va = {v8[0], v8[1], v8[2], v8[3]};
        float4 vb = {v8[4], v8[5], v8[6], v8[7]};
        float* dst = h1 + (size_t)n * 512 + h * 64 + cg * 8;
        *reinterpret_cast<float4*>(dst)     = va;
        *reinterpret_cast<float4*>(dst + 4) = vb;
    }
}

// ---------------- layer 2 ----------------

// 16 rows x 64 cols per block, 256 thr = 4 waves; wave owns 4 rows.
// 32 KB LDS -> 5 blocks/CU.
__global__ __launch_bounds__(256) void k_gemm2(const float* __restrict__ h1,
        const float* __restrict__ Wl, const float* __restrict__ Wr,
        float* __restrict__ xw2) {
    __shared__ float hs[16 * 512];       // 32 KB
    int t = threadIdx.x;
    int wave = t >> 6, j = t & 63;
    int n0 = blockIdx.x * 16;
    {
        float4* hdst = reinterpret_cast<float4*>(hs);
        for (int i = t; i < 16 * 128; i += 256) {
            int rrow = i >> 7;
            int grow = n0 + rrow;
            grow = (grow < N_NODES) ? grow : (N_NODES - 1);
            hdst[i] = reinterpret_cast<const float4*>(
                          h1 + (size_t)grow * 512)[i & 127];
        }
    }
    __syncthreads();
    const float* W = (j < 32) ? (Wl + j) : (Wr + (j - 32));
    float acc[4];
#pragma unroll
    for (int r = 0; r < 4; ++r) acc[r] = 0.f;
    for (int k = 0; k < 512; k += 4) {
        float w0 = W[(size_t)(k + 0) * 32];
        float w1 = W[(size_t)(k + 1) * 32];
        float w2 = W[(size_t)(k + 2) * 32];
        float w3 = W[(size_t)(k + 3) * 32];
#pragma unroll
        for (int r = 0; r < 4; ++r) {
            float4 a = *reinterpret_cast<const float4*>(
                &hs[(wave * 4 + r) * 512 + k]);
            acc[r] += a.x * w0 + a.y * w1 + a.z * w2 + a.w * w3;
        }
    }
#pragma unroll
    for (int r = 0; r < 4; ++r) {
        int grow = n0 + wave * 4 + r;
        if (grow < N_NODES) xw2[(size_t)grow * 64 + j] = acc[r];
    }
}

// Fused edge+node layer 2 + log_softmax: block = 4 nodes, wave = node,
// barrier-free. Full-chunk loop + masked tail.
__global__ __launch_bounds__(256) void k_node2f(const int* __restrict__ offs,
        const int* __restrict__ ssrc, const float* __restrict__ xw2,
        const float* __restrict__ att2, const float* __restrict__ b2,
        float* __restrict__ out) {
    int t = threadIdx.x;
    int wave = t >> 6, lane = t & 63;
    int n = blockIdx.x * 4 + wave;
    if (n >= N_NODES) return;
    int ej = lane >> 3;
    int cg = lane & 7;
    int beg = offs[n], dcnt = offs[n + 1] - beg;
    float4 xr = *reinterpret_cast<const float4*>(
                    xw2 + (size_t)n * 64 + 32 + cg * 4);
    float4 at = *reinterpret_cast<const float4*>(att2 + cg * 4);
    float l = 0.f;
    float4 ac = {0.f, 0.f, 0.f, 0.f};
    const int* sp = ssrc + beg;
    const char* xwbase = reinterpret_cast<const char*>(xw2) + cg * 16;
    auto ld_off = [&](int i1) -> int {
        int i1c = (i1 < dcnt) ? i1 : (dcnt - 1);
        return sp[i1c] << 8;
    };
    auto ld_row = [&](int off) -> float4 {
        return *reinterpret_cast<const float4*>(xwbase + off);
    };
    int full = dcnt & ~15;
    float4 uA = ld_row(ld_off(ej));
    float4 uB = ld_row(ld_off(8 + ej));
    int oA1 = ld_off(16 + ej), oB1 = ld_off(24 + ej);
    for (int base = 0; base < full; base += 16) {
        float4 uA1 = ld_row(oA1), uB1 = ld_row(oB1);
        int oA2 = ld_off(base + 32 + ej);
        int oB2 = ld_off(base + 40 + ej);
        float pA0 = lrelu(uA.x + xr.x) * at.x + lrelu(uA.z + xr.z) * at.z;
        float pA1 = lrelu(uA.y + xr.y) * at.y + lrelu(uA.w + xr.w) * at.w;
        float pB0 = lrelu(uB.x + xr.x) * at.x + lrelu(uB.z + xr.z) * at.z;
        float pB1 = lrelu(uB.y + xr.y) * at.y + lrelu(uB.w + xr.w) * at.w;
        float wA = __expf(fminf(red8_dpp(pA0 + pA1), 60.f));
        float wB = __expf(fminf(red8_dpp(pB0 + pB1), 60.f));
        l += wA + wB;
        ac.x += wA * uA.x + wB * uB.x;
        ac.y += wA * uA.y + wB * uB.y;
        ac.z += wA * uA.z + wB * uB.z;
        ac.w += wA * uA.w + wB * uB.w;
        uA = uA1; uB = uB1; oA1 = oA2; oB1 = oB2;
    }
    if (full < dcnt) {
        float pA0 = lrelu(uA.x + xr.x) * at.x + lrelu(uA.z + xr.z) * at.z;
        float pA1 = lrelu(uA.y + xr.y) * at.y + lrelu(uA.w + xr.w) * at.w;
        float pB0 = lrelu(uB.x + xr.x) * at.x + lrelu(uB.z + xr.z) * at.z;
        float pB1 = lrelu(uB.y + xr.y) * at.y + lrelu(uB.w + xr.w) * at.w;
        float pA = red8_dpp(pA0 + pA1);
        float pB = red8_dpp(pB0 + pB1);
        if (full + ej >= dcnt)     pA = -1e30f;
        if (full + 8 + ej >= dcnt) pB = -1e30f;
        float wA = __expf(fminf(pA, 60.f));
        float wB = __expf(fminf(pB, 60.f));
        l += wA + wB;
        ac.x += wA * uA.x + wB * uB.x;
        ac.y += wA * uA.y + wB * uB.y;
        ac.z += wA * uA.z + wB * uB.z;
        ac.w += wA * uA.w + wB * uB.w;
    }
    l = ror8_add(l); l += __shfl_xor(l, 16); l += __shfl_xor(l, 32);
    ac.x = ror8_add(ac.x); ac.x += __shfl_xor(ac.x, 16); ac.x += __shfl_xor(ac.x, 32);
    ac.y = ror8_add(ac.y); ac.y += __shfl_xor(ac.y, 16); ac.y += __shfl_xor(ac.y, 32);
    ac.z = ror8_add(ac.z); ac.z += __shfl_xor(ac.z, 16); ac.z += __shfl_xor(ac.z, 32);
    ac.w = ror8_add(ac.w); ac.w += __shfl_xor(ac.w, 16); ac.w += __shfl_xor(ac.w, 32);
    float inv = 1.f / (l + 1e-16f);
    float4 bb = *reinterpret_cast<const float4*>(b2 + cg * 4);
    float4 v;
    v.x = ac.x * inv + bb.x; v.y = ac.y * inv + bb.y;
    v.z = ac.z * inv + bb.z; v.w = ac.w * inv + bb.w;
    // log_softmax over 32 channels (8-lane DPP; ej groups identical)
    float mx = red8max_dpp(fmaxf(fmaxf(v.x, v.y), fmaxf(v.z, v.w)));
    float se = red8_dpp(__expf(v.x - mx) + __expf(v.y - mx)
                      + __expf(v.z - mx) + __expf(v.w - mx));
    float ls = __logf(se);
    v.x = v.x - mx - ls; v.y = v.y - mx - ls;
    v.z = v.z - mx - ls; v.w = v.w - mx - ls;
    if (ej == 0)
        *reinterpret_cast<float4*>(out + (size_t)n * 32 + cg * 4) = v;
}

// ---------------- launch ----------------

extern "C" void kernel_launch(void* const* d_in, const int* in_sizes, int n_in,
                              void* d_out, int out_size, void* d_ws, size_t ws_size,
                              hipStream_t stream) {
    (void)in_sizes; (void)n_in; (void)out_size; (void)ws_size;
    const float* x    = (const float*)d_in[0];
    const int*   ei   = (const int*)d_in[1];
    const float* W1l  = (const float*)d_in[2];
    const float* W1r  = (const float*)d_in[3];
    const float* att1 = (const float*)d_in[4];
    const float* b1   = (const float*)d_in[5];
    const float* W2l  = (const float*)d_in[6];
    const float* W2r  = (const float*)d_in[7];
    const float* att2 = (const float*)d_in[8];
    const float* b2   = (const float*)d_in[9];
    float* outp = (float*)d_out;

    char* ws = (char*)d_ws;
    size_t o = 0;
    auto alloc = [&](size_t bytes) {
        char* p = ws + o;
        o = (o + bytes + 255) & ~(size_t)255;
        return p;
    };
    unsigned short* xl1b = (unsigned short*)alloc((size_t)N_NODES * 512 * 2);
    float* xr1    = (float*)alloc((size_t)N_NODES * 512 * 4);
    float* h1     = (float*)alloc((size_t)N_NODES * 512 * 4);
    float* xw2    = (float*)alloc((size_t)N_NODES * 64 * 4);
    unsigned short* Abf = (unsigned short*)alloc((size_t)N_NODES * 512 * 2);
    unsigned short* Bbf = (unsigned short*)alloc((size_t)1024 * 512 * 2);
    int*   deg    = (int*)alloc((size_t)N_NODES * 4);
    int*   offs   = (int*)alloc((size_t)(N_NODES + 1) * 4);
    int*   ssrc   = (int*)alloc((size_t)ET * 4);

    hipMemsetAsync(deg, 0, (size_t)N_NODES * 4, stream);

    k_prep   <<<NB_COUNT + NB_CONVX + NB_CONVW, 256, 0, stream>>>(
                 ei, deg, x, Abf, W1l, W1r, Bbf);
    k_scan   <<<1,                    1024, 0, stream>>>(deg, offs);
    k_scatter<<<(ET + 255) / 256,      256, 0, stream>>>(ei, offs, deg, ssrc);
    k_mfma1  <<<dim3(79, 8),           256, 0, stream>>>(Abf, Bbf, xl1b, xr1);
    k_node1f <<<N_NODES,               512, 0, stream>>>(offs, ssrc, xl1b, xr1, att1, b1, h1);
    k_gemm2  <<<(N_NODES + 15) / 16,   256, 0, stream>>>(h1, W2l, W2r, xw2);
    k_node2f <<<(N_NODES + 3) / 4,     256, 0, stream>>>(offs, ssrc, xw2, att2, b2, outp);
}

// Round 19
// 237.864 us; speedup vs baseline: 1.2608x; 1.0845x over previous
//
#include <hip/hip_runtime.h>
#include <hip/hip_bf16.h>

// GATv2 x2 on MI355X — R19: tail-byte cut.
//  - h1 and xr1 stored bf16 (separate arrays; xl1b footprint unchanged for L2
//    residency). h1/xr1 HBM roundtrips halve (~40 MB saved).
//  - gemm2 -> k_mfma2 (bf16 MFMA, M=10000 N=64 K=512); W2 converted to
//    Bt2[64][512] bf16 inside k_prep. Same verified fragment/epilogue
//    pattern as k_mfma1.
//  - node kernels unchanged from R18 (barrier-free, C=16, DPP, tail-split).

constexpr int N_NODES = 10000;
constexpr int N_EDGES = 320000;
constexpr int ET      = N_EDGES + N_NODES;   // 330000 incl. self loops
constexpr float NEG_SLOPE = 0.2f;

constexpr int NB_COUNT  = (ET + 255) / 256;          // 1290
constexpr int NB_CONVX  = (N_NODES * 64) / 256;      // 2500
constexpr int NB_CONVW  = (1024 * 64) / 256;         // 256
constexpr int NB_CONVW2 = (64 * 128) / 256;          // 32  (64 rows x 128 k-quads)

typedef __attribute__((ext_vector_type(8))) short short8;
typedef __attribute__((ext_vector_type(8))) unsigned short ushort8_t;
typedef __attribute__((ext_vector_type(4))) float floatx4;

__device__ __forceinline__ float lrelu(float a) {
    return fmaxf(a, NEG_SLOPE * a);
}
__device__ __forceinline__ unsigned short f2bf(float f) {   // RNE
    unsigned u = __float_as_uint(f);
    unsigned r = u + 0x7FFFu + ((u >> 16) & 1u);
    return (unsigned short)(r >> 16);
}
__device__ __forceinline__ float bf2f(unsigned short h) {
    return __uint_as_float((unsigned)h << 16);
}
// sum over each aligned group of 8 lanes, result in all 8 (pure VALU)
__device__ __forceinline__ float red8_dpp(float p) {
    int x;
    x = __builtin_amdgcn_update_dpp(0, __float_as_int(p), 0xB1, 0xF, 0xF, true);
    p += __int_as_float(x);                  // quad_perm [1,0,3,2]
    x = __builtin_amdgcn_update_dpp(0, __float_as_int(p), 0x4E, 0xF, 0xF, true);
    p += __int_as_float(x);                  // quad_perm [2,3,0,1]
    x = __builtin_amdgcn_update_dpp(0, __float_as_int(p), 0x141, 0xF, 0xF, true);
    p += __int_as_float(x);                  // row_half_mirror
    return p;
}
__device__ __forceinline__ float red8max_dpp(float p) {
    int x;
    x = __builtin_amdgcn_update_dpp(0, __float_as_int(p), 0xB1, 0xF, 0xF, true);
    p = fmaxf(p, __int_as_float(x));
    x = __builtin_amdgcn_update_dpp(0, __float_as_int(p), 0x4E, 0xF, 0xF, true);
    p = fmaxf(p, __int_as_float(x));
    x = __builtin_amdgcn_update_dpp(0, __float_as_int(p), 0x141, 0xF, 0xF, true);
    p = fmaxf(p, __int_as_float(x));
    return p;
}
// pairwise add with lane^8 partner (row_ror:8 within 16-lane rows)
__device__ __forceinline__ float ror8_add(float p) {
    int x = __builtin_amdgcn_update_dpp(0, __float_as_int(p), 0x128, 0xF, 0xF, true);
    return p + __int_as_float(x);
}

// ------- fused prep: deg count + conv_x + conv_w1 + conv_w2 -------

__global__ __launch_bounds__(256) void k_prep(const int* __restrict__ ei,
        int* __restrict__ deg, const float* __restrict__ x,
        unsigned short* __restrict__ A, const float* __restrict__ Wl,
        const float* __restrict__ Wr, unsigned short* __restrict__ Bt,
        const float* __restrict__ W2l, const float* __restrict__ W2r,
        unsigned short* __restrict__ Bt2) {
    int b = blockIdx.x, t = threadIdx.x;
    if (b < NB_COUNT) {
        int e = b * 256 + t;
        if (e >= ET) return;
        int d = (e < N_EDGES) ? ei[N_EDGES + e] : (e - N_EDGES);
        atomicAdd(&deg[d], 1);
    } else if (b < NB_COUNT + NB_CONVX) {
        int idx = (b - NB_COUNT) * 256 + t;       // < N_NODES*64
        int m = idx >> 6, kg = (idx & 63) << 2;
        float4 v = *reinterpret_cast<const float4*>(x + (size_t)m * 256 + kg);
        ushort4 hi = make_ushort4(f2bf(v.x), f2bf(v.y), f2bf(v.z), f2bf(v.w));
        ushort4 lo = make_ushort4(f2bf(v.x - bf2f(hi.x)), f2bf(v.y - bf2f(hi.y)),
                                  f2bf(v.z - bf2f(hi.z)), f2bf(v.w - bf2f(hi.w)));
        size_t base = (size_t)m * 512 + kg;
        *reinterpret_cast<ushort4*>(A + base)       = hi;
        *reinterpret_cast<ushort4*>(A + base + 256) = lo;
    } else if (b < NB_COUNT + NB_CONVX + NB_CONVW) {
        int idx = (b - NB_COUNT - NB_CONVX) * 256 + t;   // < 1024*64
        int n = idx >> 6, kg = (idx & 63) << 2;
        const float* src = (n < 512) ? (Wl + n) : (Wr + (n - 512));
        float v0 = src[(size_t)(kg + 0) * 512];
        float v1 = src[(size_t)(kg + 1) * 512];
        float v2 = src[(size_t)(kg + 2) * 512];
        float v3 = src[(size_t)(kg + 3) * 512];
        ushort4 hi = make_ushort4(f2bf(v0), f2bf(v1), f2bf(v2), f2bf(v3));
        size_t base = (size_t)n * 512 + kg;
        *reinterpret_cast<ushort4*>(Bt + base)       = hi;
        *reinterpret_cast<ushort4*>(Bt + base + 256) = hi;   // duplicated seg
    } else {
        int idx = (b - NB_COUNT - NB_CONVX - NB_CONVW) * 256 + t;  // < 64*128
        int j = idx >> 7, kg = (idx & 127) << 2;
        const float* src = (j < 32) ? (W2l + j) : (W2r + (j - 32));
        float v0 = src[(size_t)(kg + 0) * 32];
        float v1 = src[(size_t)(kg + 1) * 32];
        float v2 = src[(size_t)(kg + 2) * 32];
        float v3 = src[(size_t)(kg + 3) * 32];
        ushort4 hi = make_ushort4(f2bf(v0), f2bf(v1), f2bf(v2), f2bf(v3));
        *reinterpret_cast<ushort4*>(Bt2 + (size_t)j * 512 + kg) = hi;
    }
}

// ---------------- CSR scan + scatter ----------------

__global__ __launch_bounds__(1024) void k_scan(const int* __restrict__ deg,
                                               int* __restrict__ offs) {
    __shared__ int part[1024];
    const int CH = 10;                       // ceil(10000/1024)
    int t = threadIdx.x;
    int base = t * CH;
    int loc[CH];
    int s = 0;
    for (int i = 0; i < CH; ++i) {
        int idx = base + i;
        int v = (idx < N_NODES) ? deg[idx] : 0;
        loc[i] = s; s += v;
    }
    part[t] = s;
    __syncthreads();
    for (int o = 1; o < 1024; o <<= 1) {
        int add = (t >= o) ? part[t - o] : 0;
        __syncthreads();
        part[t] += add;
        __syncthreads();
    }
    int excl = part[t] - s;
    for (int i = 0; i < CH; ++i) {
        int idx = base + i;
        if (idx < N_NODES) offs[idx] = excl + loc[i];
    }
    if (t == 1023) offs[N_NODES] = part[1023];
}

// deg doubles as countdown cursor: pos = offs[d] + (--deg[d])
__global__ void k_scatter(const int* __restrict__ ei, const int* __restrict__ offs,
                          int* __restrict__ deg, int* __restrict__ ssrc) {
    int e = blockIdx.x * 256 + threadIdx.x;
    if (e >= ET) return;
    int s, d;
    if (e < N_EDGES) { s = ei[e]; d = ei[N_EDGES + e]; }
    else             { s = d = e - N_EDGES; }
    int pos = offs[d] + atomicAdd(&deg[d], -1) - 1;
    ssrc[pos] = s;
}

// ---------------- layer 1 MFMA GEMM ----------------

// 128x128 tile, M=10000 N=1024 K=512, grid (79,8), 4 waves/block.
// xl columns (<512) -> xl1b bf16; xr columns (>=512) -> xr1b bf16.
__global__ __launch_bounds__(256) void k_mfma1(const unsigned short* __restrict__ A,
        const unsigned short* __restrict__ Bt, unsigned short* __restrict__ xl1b,
        unsigned short* __restrict__ xr1b) {
    __shared__ unsigned short As[128 * 40];   // stride 40: 2-way max = free
    __shared__ unsigned short Bs[128 * 40];
    int t = threadIdx.x;
    int wave = t >> 6, L = t & 63;
    int wm = wave & 1, wn = wave >> 1;
    int row0 = blockIdx.x * 128, n0 = blockIdx.y * 128;
    int q = L >> 4, rr = L & 15;
    floatx4 acc[4][4];
#pragma unroll
    for (int i = 0; i < 4; ++i)
#pragma unroll
        for (int j = 0; j < 4; ++j) acc[i][j] = (floatx4){0.f, 0.f, 0.f, 0.f};
    int ra = t >> 2,        ka = (t & 3) * 8;
    int rb = (t + 256) >> 2, kb = ((t + 256) & 3) * 8;
    int gma = row0 + ra; gma = (gma < N_NODES) ? gma : (N_NODES - 1);
    int gmb = row0 + rb; gmb = (gmb < N_NODES) ? gmb : (N_NODES - 1);
    for (int kc = 0; kc < 512; kc += 32) {
        __syncthreads();
        *reinterpret_cast<uint4*>(&As[ra * 40 + ka]) =
            *reinterpret_cast<const uint4*>(A + (size_t)gma * 512 + kc + ka);
        *reinterpret_cast<uint4*>(&As[rb * 40 + kb]) =
            *reinterpret_cast<const uint4*>(A + (size_t)gmb * 512 + kc + kb);
        *reinterpret_cast<uint4*>(&Bs[ra * 40 + ka]) =
            *reinterpret_cast<const uint4*>(Bt + (size_t)(n0 + ra) * 512 + kc + ka);
        *reinterpret_cast<uint4*>(&Bs[rb * 40 + kb]) =
            *reinterpret_cast<const uint4*>(Bt + (size_t)(n0 + rb) * 512 + kc + kb);
        __syncthreads();
        short8 af[4], bf[4];
#pragma unroll
        for (int st = 0; st < 4; ++st)
            af[st] = *reinterpret_cast<const short8*>(
                &As[(wm * 64 + st * 16 + rr) * 40 + q * 8]);
#pragma unroll
        for (int st = 0; st < 4; ++st)
            bf[st] = *reinterpret_cast<const short8*>(
                &Bs[(wn * 64 + st * 16 + rr) * 40 + q * 8]);
#pragma unroll
        for (int i = 0; i < 4; ++i)
#pragma unroll
            for (int j = 0; j < 4; ++j)
                acc[i][j] = __builtin_amdgcn_mfma_f32_16x16x32_bf16(
                    af[i], bf[j], acc[i][j], 0, 0, 0);
    }
    // epilogue: C/D layout col=lane&15, row=(lane>>4)*4+reg  [m89/m91]
#pragma unroll
    for (int j = 0; j < 4; ++j) {
        int gc = n0 + wn * 64 + j * 16 + rr;
        unsigned short* dst = (gc < 512) ? xl1b : xr1b;
        int col = (gc < 512) ? gc : (gc - 512);
#pragma unroll
        for (int i = 0; i < 4; ++i)
#pragma unroll
            for (int r = 0; r < 4; ++r) {
                int gr = row0 + wm * 64 + i * 16 + q * 4 + r;
                if (gr < N_NODES)
                    dst[(size_t)gr * 512 + col] = f2bf(acc[i][j][r]);
            }
    }
}

// Fused edge+node layer 1: block = node (512 thr = 8 waves, wave = head),
// barrier-free. Full-chunk hot loop + one masked tail. h1 stored bf16.
__global__ __launch_bounds__(512) void k_node1f(const int* __restrict__ offs,
        const int* __restrict__ ssrc, const unsigned short* __restrict__ xl1b,
        const unsigned short* __restrict__ xr1b, const float* __restrict__ att1,
        const float* __restrict__ b1, unsigned short* __restrict__ h1b) {
    int n = blockIdx.x;
    int t = threadIdx.x;
    int h = t >> 6, lane = t & 63;
    int beg = offs[n], dcnt = offs[n + 1] - beg;
    int ej = lane >> 3;                  // edge slot
    int cg = lane & 7;                   // channel group of 8
    float xrv[8], atv[8];
    {
        ushort8_t xru = *reinterpret_cast<const ushort8_t*>(
            xr1b + (size_t)n * 512 + h * 64 + cg * 8);
        const float* atrow = att1 + h * 64 + cg * 8;
        float4 c0 = *reinterpret_cast<const float4*>(atrow);
        float4 c1 = *reinterpret_cast<const float4*>(atrow + 4);
#pragma unroll
        for (int i = 0; i < 8; ++i) xrv[i] = bf2f(xru[i]);
        atv[0]=c0.x; atv[1]=c0.y; atv[2]=c0.z; atv[3]=c0.w;
        atv[4]=c1.x; atv[5]=c1.y; atv[6]=c1.z; atv[7]=c1.w;
    }
    float l = 0.f;
    float acc8[8];
#pragma unroll
    for (int i = 0; i < 8; ++i) acc8[i] = 0.f;
    const int* sp = ssrc + beg;
    const char* xlbase = reinterpret_cast<const char*>(xl1b) + h * 128 + cg * 16;

    auto ld_off = [&](int i1) -> int {
        int i1c = (i1 < dcnt) ? i1 : (dcnt - 1);   // dcnt >= 1 (self loop)
        return sp[i1c] << 10;
    };
    auto ld_row = [&](int off) -> ushort8_t {
        return *reinterpret_cast<const ushort8_t*>(xlbase + off);
    };
    int full = dcnt & ~15;               // edges covered by full 16-chunks
    ushort8_t uA = ld_row(ld_off(ej));
    ushort8_t uB = ld_row(ld_off(8 + ej));
    int oA1 = ld_off(16 + ej), oB1 = ld_off(24 + ej);
    for (int base = 0; base < full; base += 16) {
        ushort8_t uA1 = ld_row(oA1), uB1 = ld_row(oB1);   // rows +1 chunk
        int oA2 = ld_off(base + 32 + ej);                 // offs +2 chunks
        int oB2 = ld_off(base + 40 + ej);
        float xsA[8], xsB[8];
#pragma unroll
        for (int i = 0; i < 8; ++i) { xsA[i] = bf2f(uA[i]); xsB[i] = bf2f(uB[i]); }
        float pA0 = 0.f, pA1 = 0.f, pB0 = 0.f, pB1 = 0.f;
#pragma unroll
        for (int i = 0; i < 4; ++i) {
            pA0 += lrelu(xsA[i] + xrv[i]) * atv[i];
            pA1 += lrelu(xsA[i + 4] + xrv[i + 4]) * atv[i + 4];
            pB0 += lrelu(xsB[i] + xrv[i]) * atv[i];
            pB1 += lrelu(xsB[i + 4] + xrv[i + 4]) * atv[i + 4];
        }
        float wA = __expf(fminf(red8_dpp(pA0 + pA1), 60.f));
        float wB = __expf(fminf(red8_dpp(pB0 + pB1), 60.f));
        l += wA + wB;
#pragma unroll
        for (int i = 0; i < 8; ++i) acc8[i] += wA * xsA[i] + wB * xsB[i];
        uA = uA1; uB = uB1; oA1 = oA2; oB1 = oB2;
    }
    if (full < dcnt) {                   // masked tail (single iteration)
        float xsA[8], xsB[8];
#pragma unroll
        for (int i = 0; i < 8; ++i) { xsA[i] = bf2f(uA[i]); xsB[i] = bf2f(uB[i]); }
        float pA0 = 0.f, pA1 = 0.f, pB0 = 0.f, pB1 = 0.f;
#pragma unroll
        for (int i = 0; i < 4; ++i) {
            pA0 += lrelu(xsA[i] + xrv[i]) * atv[i];
            pA1 += lrelu(xsA[i + 4] + xrv[i + 4]) * atv[i + 4];
            pB0 += lrelu(xsB[i] + xrv[i]) * atv[i];
            pB1 += lrelu(xsB[i + 4] + xrv[i + 4]) * atv[i + 4];
        }
        float pA = red8_dpp(pA0 + pA1);
        float pB = red8_dpp(pB0 + pB1);
        if (full + ej >= dcnt)     pA = -1e30f;
        if (full + 8 + ej >= dcnt) pB = -1e30f;
        float wA = __expf(fminf(pA, 60.f));
        float wB = __expf(fminf(pB, 60.f));
        l += wA + wB;
#pragma unroll
        for (int i = 0; i < 8; ++i) acc8[i] += wA * xsA[i] + wB * xsB[i];
    }
    // reduce over the 8 edge slots: DPP ror8 + swizzle xor16/32
    l = ror8_add(l); l += __shfl_xor(l, 16); l += __shfl_xor(l, 32);
#pragma unroll
    for (int i = 0; i < 8; ++i) {
        acc8[i] = ror8_add(acc8[i]);
        acc8[i] += __shfl_xor(acc8[i], 16);
        acc8[i] += __shfl_xor(acc8[i], 32);
    }
    float inv = 1.f / (l + 1e-16f);
    if (ej == 0) {
        const float* brow = b1 + h * 64 + cg * 8;
        ushort8_t vout;
#pragma unroll
        for (int i = 0; i < 8; ++i) {
            float v = acc8[i] * inv + brow[i];
            v = (v > 0.f) ? v : (__expf(v) - 1.f);   // elu (fast exp)
            vout[i] = f2bf(v);
        }
        *reinterpret_cast<ushort8_t*>(
            h1b + (size_t)n * 512 + h * 64 + cg * 8) = vout;
    }
}

// ---------------- layer 2: MFMA GEMM ----------------

// M=10000, N=64, K=512 bf16. 128-row tiles, 4 waves (wave = 32 rows),
// 2x4 fragments/wave. Grid: 79 blocks.
__global__ __launch_bounds__(256) void k_mfma2(const unsigned short* __restrict__ h1b,
        const unsigned short* __restrict__ Bt2, float* __restrict__ xw2) {
    __shared__ unsigned short Hs[128 * 40];
    __shared__ unsigned short Ws[64 * 40];
    int t = threadIdx.x;
    int wave = t >> 6, L = t & 63;
    int row0 = blockIdx.x * 128;
    int q = L >> 4, rr = L & 15;
    floatx4 acc[2][4];
#pragma unroll
    for (int i = 0; i < 2; ++i)
#pragma unroll
        for (int j = 0; j < 4; ++j) acc[i][j] = (floatx4){0.f, 0.f, 0.f, 0.f};
    int ra = t >> 2,        ka = (t & 3) * 8;      // Hs chunk 1 (rows 0-63)
    int rb = (t + 256) >> 2, kb = ((t + 256) & 3) * 8;  // rows 64-127
    int gma = row0 + ra; gma = (gma < N_NODES) ? gma : (N_NODES - 1);
    int gmb = row0 + rb; gmb = (gmb < N_NODES) ? gmb : (N_NODES - 1);
    for (int kc = 0; kc < 512; kc += 32) {
        __syncthreads();
        *reinterpret_cast<uint4*>(&Hs[ra * 40 + ka]) =
            *reinterpret_cast<const uint4*>(h1b + (size_t)gma * 512 + kc + ka);
        *reinterpret_cast<uint4*>(&Hs[rb * 40 + kb]) =
            *reinterpret_cast<const uint4*>(h1b + (size_t)gmb * 512 + kc + kb);
        // Ws: 64 rows x 4 chunks = 256 -> 1 per thread
        *reinterpret_cast<uint4*>(&Ws[ra * 40 + ka]) =
            *reinterpret_cast<const uint4*>(Bt2 + (size_t)(ra & 63) * 512 + kc + ka);
        __syncthreads();
        short8 af[2], bf[4];
#pragma unroll
        for (int i = 0; i < 2; ++i)
            af[i] = *reinterpret_cast<const short8*>(
                &Hs[(wave * 32 + i * 16 + rr) * 40 + q * 8]);
#pragma unroll
        for (int j = 0; j < 4; ++j)
            bf[j] = *reinterpret_cast<const short8*>(
                &Ws[(j * 16 + rr) * 40 + q * 8]);
#pragma unroll
        for (int i = 0; i < 2; ++i)
#pragma unroll
            for (int j = 0; j < 4; ++j)
                acc[i][j] = __builtin_amdgcn_mfma_f32_16x16x32_bf16(
                    af[i], bf[j], acc[i][j], 0, 0, 0);
    }
    // epilogue: col=lane&15, row=(lane>>4)*4+reg
#pragma unroll
    for (int j = 0; j < 4; ++j) {
        int gc = j * 16 + rr;
#pragma unroll
        for (int i = 0; i < 2; ++i)
#pragma unroll
            for (int r = 0; r < 4; ++r) {
                int gr = row0 + wave * 32 + i * 16 + q * 4 + r;
                if (gr < N_NODES) xw2[(size_t)gr * 64 + gc] = acc[i][j][r];
            }
    }
}

// Fused edge+node layer 2 + log_softmax: block = 4 nodes, wave = node,
// barrier-free. Full-chunk loop + masked tail.
__global__ __launch_bounds__(256) void k_node2f(const int* __restrict__ offs,
        const int* __restrict__ ssrc, const float* __restrict__ xw2,
        const float* __restrict__ att2, const float* __restrict__ b2,
        float* __restrict__ out) {
    int t = threadIdx.x;
    int wave = t >> 6, lane = t & 63;
    int n = blockIdx.x * 4 + wave;
    if (n >= N_NODES) return;
    int ej = lane >> 3;
    int cg = lane & 7;
    int beg = offs[n], dcnt = offs[n + 1] - beg;
    float4 xr = *reinterpret_cast<const float4*>(
                    xw2 + (size_t)n * 64 + 32 + cg * 4);
    float4 at = *reinterpret_cast<const float4*>(att2 + cg * 4);
    float l = 0.f;
    float4 ac = {0.f, 0.f, 0.f, 0.f};
    const int* sp = ssrc + beg;
    const char* xwbase = reinterpret_cast<const char*>(xw2) + cg * 16;
    auto ld_off = [&](int i1) -> int {
        int i1c = (i1 < dcnt) ? i1 : (dcnt - 1);
        return sp[i1c] << 8;
    };
    auto ld_row = [&](int off) -> float4 {
        return *reinterpret_cast<const float4*>(xwbase + off);
    };
    int full = dcnt & ~15;
    float4 uA = ld_row(ld_off(ej));
    float4 uB = ld_row(ld_off(8 + ej));
    int oA1 = ld_off(16 + ej), oB1 = ld_off(24 + ej);
    for (int base = 0; base < full; base += 16) {
        float4 uA1 = ld_row(oA1), uB1 = ld_row(oB1);
        int oA2 = ld_off(base + 32 + ej);
        int oB2 = ld_off(base + 40 + ej);
        float pA0 = lrelu(uA.x + xr.x) * at.x + lrelu(uA.z + xr.z) * at.z;
        float pA1 = lrelu(uA.y + xr.y) * at.y + lrelu(uA.w + xr.w) * at.w;
        float pB0 = lrelu(uB.x + xr.x) * at.x + lrelu(uB.z + xr.z) * at.z;
        float pB1 = lrelu(uB.y + xr.y) * at.y + lrelu(uB.w + xr.w) * at.w;
        float wA = __expf(fminf(red8_dpp(pA0 + pA1), 60.f));
        float wB = __expf(fminf(red8_dpp(pB0 + pB1), 60.f));
        l += wA + wB;
        ac.x += wA * uA.x + wB * uB.x;
        ac.y += wA * uA.y + wB * uB.y;
        ac.z += wA * uA.z + wB * uB.z;
        ac.w += wA * uA.w + wB * uB.w;
        uA = uA1; uB = uB1; oA1 = oA2; oB1 = oB2;
    }
    if (full < dcnt) {
        float pA0 = lrelu(uA.x + xr.x) * at.x + lrelu(uA.z + xr.z) * at.z;
        float pA1 = lrelu(uA.y + xr.y) * at.y + lrelu(uA.w + xr.w) * at.w;
        float pB0 = lrelu(uB.x + xr.x) * at.x + lrelu(uB.z + xr.z) * at.z;
        float pB1 = lrelu(uB.y + xr.y) * at.y + lrelu(uB.w + xr.w) * at.w;
        float pA = red8_dpp(pA0 + pA1);
        float pB = red8_dpp(pB0 + pB1);
        if (full + ej >= dcnt)     pA = -1e30f;
        if (full + 8 + ej >= dcnt) pB = -1e30f;
        float wA = __expf(fminf(pA, 60.f));
        float wB = __expf(fminf(pB, 60.f));
        l += wA + wB;
        ac.x += wA * uA.x + wB * uB.x;
        ac.y += wA * uA.y + wB * uB.y;
        ac.z += wA * uA.z + wB * uB.z;
        ac.w += wA * uA.w + wB * uB.w;
    }
    l = ror8_add(l); l += __shfl_xor(l, 16); l += __shfl_xor(l, 32);
    ac.x = ror8_add(ac.x); ac.x += __shfl_xor(ac.x, 16); ac.x += __shfl_xor(ac.x, 32);
    ac.y = ror8_add(ac.y); ac.y += __shfl_xor(ac.y, 16); ac.y += __shfl_xor(ac.y, 32);
    ac.z = ror8_add(ac.z); ac.z += __shfl_xor(ac.z, 16); ac.z += __shfl_xor(ac.z, 32);
    ac.w = ror8_add(ac.w); ac.w += __shfl_xor(ac.w, 16); ac.w += __shfl_xor(ac.w, 32);
    float inv = 1.f / (l + 1e-16f);
    float4 bb = *reinterpret_cast<const float4*>(b2 + cg * 4);
    float4 v;
    v.x = ac.x * inv + bb.x; v.y = ac.y * inv + bb.y;
    v.z = ac.z * inv + bb.z; v.w = ac.w * inv + bb.w;
    // log_softmax over 32 channels (8-lane DPP; ej groups identical)
    float mx = red8max_dpp(fmaxf(fmaxf(v.x, v.y), fmaxf(v.z, v.w)));
    float se = red8_dpp(__expf(v.x - mx) + __expf(v.y - mx)
                      + __expf(v.z - mx) + __expf(v.w - mx));
    float ls = __logf(se);
    v.x = v.x - mx - ls; v.y = v.y - mx - ls;
    v.z = v.z - mx - ls; v.w = v.w - mx - ls;
    if (ej == 0)
        *reinterpret_cast<float4*>(out + (size_t)n * 32 + cg * 4) = v;
}

// ---------------- launch ----------------

extern "C" void kernel_launch(void* const* d_in, const int* in_sizes, int n_in,
                              void* d_out, int out_size, void* d_ws, size_t ws_size,
                              hipStream_t stream) {
    (void)in_sizes; (void)n_in; (void)out_size; (void)ws_size;
    const float* x    = (const float*)d_in[0];
    const int*   ei   = (const int*)d_in[1];
    const float* W1l  = (const float*)d_in[2];
    const float* W1r  = (const float*)d_in[3];
    const float* att1 = (const float*)d_in[4];
    const float* b1   = (const float*)d_in[5];
    const float* W2l  = (const float*)d_in[6];
    const float* W2r  = (const float*)d_in[7];
    const float* att2 = (const float*)d_in[8];
    const float* b2   = (const float*)d_in[9];
    float* outp = (float*)d_out;

    char* ws = (char*)d_ws;
    size_t o = 0;
    auto alloc = [&](size_t bytes) {
        char* p = ws + o;
        o = (o + bytes + 255) & ~(size_t)255;
        return p;
    };
    unsigned short* xl1b = (unsigned short*)alloc((size_t)N_NODES * 512 * 2);
    unsigned short* xr1b = (unsigned short*)alloc((size_t)N_NODES * 512 * 2);
    unsigned short* h1b  = (unsigned short*)alloc((size_t)N_NODES * 512 * 2);
    float* xw2    = (float*)alloc((size_t)N_NODES * 64 * 4);
    unsigned short* Abf = (unsigned short*)alloc((size_t)N_NODES * 512 * 2);
    unsigned short* Bbf = (unsigned short*)alloc((size_t)1024 * 512 * 2);
    unsigned short* Bt2 = (unsigned short*)alloc((size_t)64 * 512 * 2);
    int*   deg    = (int*)alloc((size_t)N_NODES * 4);
    int*   offs   = (int*)alloc((size_t)(N_NODES + 1) * 4);
    int*   ssrc   = (int*)alloc((size_t)ET * 4);

    hipMemsetAsync(deg, 0, (size_t)N_NODES * 4, stream);

    k_prep   <<<NB_COUNT + NB_CONVX + NB_CONVW + NB_CONVW2, 256, 0, stream>>>(
                 ei, deg, x, Abf, W1l, W1r, Bbf, W2l, W2r, Bt2);
    k_scan   <<<1,                    1024, 0, stream>>>(deg, offs);
    k_scatter<<<(ET + 255) / 256,      256, 0, stream>>>(ei, offs, deg, ssrc);
    k_mfma1  <<<dim3(79, 8),           256, 0, stream>>>(Abf, Bbf, xl1b, xr1b);
    k_node1f <<<N_NODES,               512, 0, stream>>>(offs, ssrc, xl1b, xr1b, att1, b1, h1b);
    k_mfma2  <<<79,                    256, 0, stream>>>(h1b, Bt2, xw2);
    k_node2f <<<(N_NODES + 3) / 4,     256, 0, stream>>>(offs, ssrc, xw2, att2, b2, outp);
}

// Round 20
// 229.974 us; speedup vs baseline: 1.3040x; 1.0343x over previous
//
#include <hip/hip_runtime.h>
#include <hip/hip_bf16.h>

// GATv2 x2 on MI355X — R20: coalesced-row gather in node1f.
//  Old: 8 head-waves per node each gathered a different 128B segment of the
//  same 1KB xl row (scattered 2-line requests, ~1.8 TB/s effective).
//  New: wave = node; lane l = (head l>>3, cg l&7) reads bytes [l*16,l*16+16)
//  -> ONE coalesced 1KB load per edge. red8_dpp over aligned 8-lane groups
//  gives all 8 head-alphas at once. Each lane owns its 8 channels across all
//  edges: no final slot-reduce, no tail masks, no dup loads, full-wave
//  coalesced h1 store. k_mfma2 retiled to 64 rows (79 -> 157 blocks).

constexpr int N_NODES = 10000;
constexpr int N_EDGES = 320000;
constexpr int ET      = N_EDGES + N_NODES;   // 330000 incl. self loops
constexpr float NEG_SLOPE = 0.2f;

constexpr int NB_COUNT  = (ET + 255) / 256;          // 1290
constexpr int NB_CONVX  = (N_NODES * 64) / 256;      // 2500
constexpr int NB_CONVW  = (1024 * 64) / 256;         // 256
constexpr int NB_CONVW2 = (64 * 128) / 256;          // 32

typedef __attribute__((ext_vector_type(8))) short short8;
typedef __attribute__((ext_vector_type(8))) unsigned short ushort8_t;
typedef __attribute__((ext_vector_type(4))) float floatx4;

__device__ __forceinline__ float lrelu(float a) {
    return fmaxf(a, NEG_SLOPE * a);
}
__device__ __forceinline__ unsigned short f2bf(float f) {   // RNE
    unsigned u = __float_as_uint(f);
    unsigned r = u + 0x7FFFu + ((u >> 16) & 1u);
    return (unsigned short)(r >> 16);
}
__device__ __forceinline__ float bf2f(unsigned short h) {
    return __uint_as_float((unsigned)h << 16);
}
// sum over each aligned group of 8 lanes, result in all 8 (pure VALU)
__device__ __forceinline__ float red8_dpp(float p) {
    int x;
    x = __builtin_amdgcn_update_dpp(0, __float_as_int(p), 0xB1, 0xF, 0xF, true);
    p += __int_as_float(x);                  // quad_perm [1,0,3,2]
    x = __builtin_amdgcn_update_dpp(0, __float_as_int(p), 0x4E, 0xF, 0xF, true);
    p += __int_as_float(x);                  // quad_perm [2,3,0,1]
    x = __builtin_amdgcn_update_dpp(0, __float_as_int(p), 0x141, 0xF, 0xF, true);
    p += __int_as_float(x);                  // row_half_mirror
    return p;
}
__device__ __forceinline__ float red8max_dpp(float p) {
    int x;
    x = __builtin_amdgcn_update_dpp(0, __float_as_int(p), 0xB1, 0xF, 0xF, true);
    p = fmaxf(p, __int_as_float(x));
    x = __builtin_amdgcn_update_dpp(0, __float_as_int(p), 0x4E, 0xF, 0xF, true);
    p = fmaxf(p, __int_as_float(x));
    x = __builtin_amdgcn_update_dpp(0, __float_as_int(p), 0x141, 0xF, 0xF, true);
    p = fmaxf(p, __int_as_float(x));
    return p;
}
// pairwise add with lane^8 partner (row_ror:8 within 16-lane rows)
__device__ __forceinline__ float ror8_add(float p) {
    int x = __builtin_amdgcn_update_dpp(0, __float_as_int(p), 0x128, 0xF, 0xF, true);
    return p + __int_as_float(x);
}

// ------- fused prep: deg count + conv_x + conv_w1 + conv_w2 -------

__global__ __launch_bounds__(256) void k_prep(const int* __restrict__ ei,
        int* __restrict__ deg, const float* __restrict__ x,
        unsigned short* __restrict__ A, const float* __restrict__ Wl,
        const float* __restrict__ Wr, unsigned short* __restrict__ Bt,
        const float* __restrict__ W2l, const float* __restrict__ W2r,
        unsigned short* __restrict__ Bt2) {
    int b = blockIdx.x, t = threadIdx.x;
    if (b < NB_COUNT) {
        int e = b * 256 + t;
        if (e >= ET) return;
        int d = (e < N_EDGES) ? ei[N_EDGES + e] : (e - N_EDGES);
        atomicAdd(&deg[d], 1);
    } else if (b < NB_COUNT + NB_CONVX) {
        int idx = (b - NB_COUNT) * 256 + t;       // < N_NODES*64
        int m = idx >> 6, kg = (idx & 63) << 2;
        float4 v = *reinterpret_cast<const float4*>(x + (size_t)m * 256 + kg);
        ushort4 hi = make_ushort4(f2bf(v.x), f2bf(v.y), f2bf(v.z), f2bf(v.w));
        ushort4 lo = make_ushort4(f2bf(v.x - bf2f(hi.x)), f2bf(v.y - bf2f(hi.y)),
                                  f2bf(v.z - bf2f(hi.z)), f2bf(v.w - bf2f(hi.w)));
        size_t base = (size_t)m * 512 + kg;
        *reinterpret_cast<ushort4*>(A + base)       = hi;
        *reinterpret_cast<ushort4*>(A + base + 256) = lo;
    } else if (b < NB_COUNT + NB_CONVX + NB_CONVW) {
        int idx = (b - NB_COUNT - NB_CONVX) * 256 + t;   // < 1024*64
        int n = idx >> 6, kg = (idx & 63) << 2;
        const float* src = (n < 512) ? (Wl + n) : (Wr + (n - 512));
        float v0 = src[(size_t)(kg + 0) * 512];
        float v1 = src[(size_t)(kg + 1) * 512];
        float v2 = src[(size_t)(kg + 2) * 512];
        float v3 = src[(size_t)(kg + 3) * 512];
        ushort4 hi = make_ushort4(f2bf(v0), f2bf(v1), f2bf(v2), f2bf(v3));
        size_t base = (size_t)n * 512 + kg;
        *reinterpret_cast<ushort4*>(Bt + base)       = hi;
        *reinterpret_cast<ushort4*>(Bt + base + 256) = hi;   // duplicated seg
    } else {
        int idx = (b - NB_COUNT - NB_CONVX - NB_CONVW) * 256 + t;  // < 64*128
        int j = idx >> 7, kg = (idx & 127) << 2;
        const float* src = (j < 32) ? (W2l + j) : (W2r + (j - 32));
        float v0 = src[(size_t)(kg + 0) * 32];
        float v1 = src[(size_t)(kg + 1) * 32];
        float v2 = src[(size_t)(kg + 2) * 32];
        float v3 = src[(size_t)(kg + 3) * 32];
        ushort4 hi = make_ushort4(f2bf(v0), f2bf(v1), f2bf(v2), f2bf(v3));
        *reinterpret_cast<ushort4*>(Bt2 + (size_t)j * 512 + kg) = hi;
    }
}

// ---------------- CSR scan + scatter ----------------

__global__ __launch_bounds__(1024) void k_scan(const int* __restrict__ deg,
                                               int* __restrict__ offs) {
    __shared__ int part[1024];
    const int CH = 10;                       // ceil(10000/1024)
    int t = threadIdx.x;
    int base = t * CH;
    int loc[CH];
    int s = 0;
    for (int i = 0; i < CH; ++i) {
        int idx = base + i;
        int v = (idx < N_NODES) ? deg[idx] : 0;
        loc[i] = s; s += v;
    }
    part[t] = s;
    __syncthreads();
    for (int o = 1; o < 1024; o <<= 1) {
        int add = (t >= o) ? part[t - o] : 0;
        __syncthreads();
        part[t] += add;
        __syncthreads();
    }
    int excl = part[t] - s;
    for (int i = 0; i < CH; ++i) {
        int idx = base + i;
        if (idx < N_NODES) offs[idx] = excl + loc[i];
    }
    if (t == 1023) offs[N_NODES] = part[1023];
}

// deg doubles as countdown cursor: pos = offs[d] + (--deg[d])
__global__ void k_scatter(const int* __restrict__ ei, const int* __restrict__ offs,
                          int* __restrict__ deg, int* __restrict__ ssrc) {
    int e = blockIdx.x * 256 + threadIdx.x;
    if (e >= ET) return;
    int s, d;
    if (e < N_EDGES) { s = ei[e]; d = ei[N_EDGES + e]; }
    else             { s = d = e - N_EDGES; }
    int pos = offs[d] + atomicAdd(&deg[d], -1) - 1;
    ssrc[pos] = s;
}

// ---------------- layer 1 MFMA GEMM ----------------

// 128x128 tile, M=10000 N=1024 K=512, grid (79,8), 4 waves/block.
__global__ __launch_bounds__(256) void k_mfma1(const unsigned short* __restrict__ A,
        const unsigned short* __restrict__ Bt, unsigned short* __restrict__ xl1b,
        unsigned short* __restrict__ xr1b) {
    __shared__ unsigned short As[128 * 40];   // stride 40: 2-way max = free
    __shared__ unsigned short Bs[128 * 40];
    int t = threadIdx.x;
    int wave = t >> 6, L = t & 63;
    int wm = wave & 1, wn = wave >> 1;
    int row0 = blockIdx.x * 128, n0 = blockIdx.y * 128;
    int q = L >> 4, rr = L & 15;
    floatx4 acc[4][4];
#pragma unroll
    for (int i = 0; i < 4; ++i)
#pragma unroll
        for (int j = 0; j < 4; ++j) acc[i][j] = (floatx4){0.f, 0.f, 0.f, 0.f};
    int ra = t >> 2,        ka = (t & 3) * 8;
    int rb = (t + 256) >> 2, kb = ((t + 256) & 3) * 8;
    int gma = row0 + ra; gma = (gma < N_NODES) ? gma : (N_NODES - 1);
    int gmb = row0 + rb; gmb = (gmb < N_NODES) ? gmb : (N_NODES - 1);
    for (int kc = 0; kc < 512; kc += 32) {
        __syncthreads();
        *reinterpret_cast<uint4*>(&As[ra * 40 + ka]) =
            *reinterpret_cast<const uint4*>(A + (size_t)gma * 512 + kc + ka);
        *reinterpret_cast<uint4*>(&As[rb * 40 + kb]) =
            *reinterpret_cast<const uint4*>(A + (size_t)gmb * 512 + kc + kb);
        *reinterpret_cast<uint4*>(&Bs[ra * 40 + ka]) =
            *reinterpret_cast<const uint4*>(Bt + (size_t)(n0 + ra) * 512 + kc + ka);
        *reinterpret_cast<uint4*>(&Bs[rb * 40 + kb]) =
            *reinterpret_cast<const uint4*>(Bt + (size_t)(n0 + rb) * 512 + kc + kb);
        __syncthreads();
        short8 af[4], bf[4];
#pragma unroll
        for (int st = 0; st < 4; ++st)
            af[st] = *reinterpret_cast<const short8*>(
                &As[(wm * 64 + st * 16 + rr) * 40 + q * 8]);
#pragma unroll
        for (int st = 0; st < 4; ++st)
            bf[st] = *reinterpret_cast<const short8*>(
                &Bs[(wn * 64 + st * 16 + rr) * 40 + q * 8]);
#pragma unroll
        for (int i = 0; i < 4; ++i)
#pragma unroll
            for (int j = 0; j < 4; ++j)
                acc[i][j] = __builtin_amdgcn_mfma_f32_16x16x32_bf16(
                    af[i], bf[j], acc[i][j], 0, 0, 0);
    }
    // epilogue: C/D layout col=lane&15, row=(lane>>4)*4+reg  [m89/m91]
#pragma unroll
    for (int j = 0; j < 4; ++j) {
        int gc = n0 + wn * 64 + j * 16 + rr;
        unsigned short* dst = (gc < 512) ? xl1b : xr1b;
        int col = (gc < 512) ? gc : (gc - 512);
#pragma unroll
        for (int i = 0; i < 4; ++i)
#pragma unroll
            for (int r = 0; r < 4; ++r) {
                int gr = row0 + wm * 64 + i * 16 + q * 4 + r;
                if (gr < N_NODES)
                    dst[(size_t)gr * 512 + col] = f2bf(acc[i][j][r]);
            }
    }
}

// Fused edge+node layer 1 — wave = node (block = 4 nodes, barrier-free).
// Lane l = (head l>>3, cg l&7). Per edge: one coalesced 1KB row load,
// red8_dpp gives all head-alphas, lane-exclusive channel accumulation.
// No final reduce, no masks; exact dcnt iterations, depth-2 prefetch.
__global__ __launch_bounds__(256) void k_node1f(const int* __restrict__ offs,
        const int* __restrict__ ssrc, const unsigned short* __restrict__ xl1b,
        const unsigned short* __restrict__ xr1b, const float* __restrict__ att1,
        const float* __restrict__ b1, unsigned short* __restrict__ h1b) {
    int t = threadIdx.x;
    int wave = t >> 6, lane = t & 63;
    int n = blockIdx.x * 4 + wave;
    if (n >= N_NODES) return;
    int beg = offs[n], dcnt = offs[n + 1] - beg;
    float xrv[8], atv[8];
    {
        ushort8_t xru = *reinterpret_cast<const ushort8_t*>(
            xr1b + (size_t)n * 512 + lane * 8);
        const float* atrow = att1 + lane * 8;
        float4 c0 = *reinterpret_cast<const float4*>(atrow);
        float4 c1 = *reinterpret_cast<const float4*>(atrow + 4);
#pragma unroll
        for (int i = 0; i < 8; ++i) xrv[i] = bf2f(xru[i]);
        atv[0]=c0.x; atv[1]=c0.y; atv[2]=c0.z; atv[3]=c0.w;
        atv[4]=c1.x; atv[5]=c1.y; atv[6]=c1.z; atv[7]=c1.w;
    }
    float l = 0.f;
    float acc8[8];
#pragma unroll
    for (int i = 0; i < 8; ++i) acc8[i] = 0.f;
    const int* sp = ssrc + beg;
    const char* xlbase = reinterpret_cast<const char*>(xl1b) + lane * 16;
    auto ld_off = [&](int i) -> int {
        int ic = (i < dcnt) ? i : (dcnt - 1);   // dcnt >= 1 (self loop)
        return sp[ic] << 10;
    };
    auto ld_row = [&](int off) -> ushort8_t {
        return *reinterpret_cast<const ushort8_t*>(xlbase + off);
    };
    ushort8_t u0 = ld_row(ld_off(0));
    ushort8_t u1 = ld_row(ld_off(1));
    for (int i = 0; i < dcnt; ++i) {
        ushort8_t u2 = ld_row(ld_off(i + 2));   // depth-2 prefetch
        float xs[8];
#pragma unroll
        for (int j = 0; j < 8; ++j) xs[j] = bf2f(u0[j]);
        float p0 = 0.f, p1 = 0.f;
#pragma unroll
        for (int j = 0; j < 4; ++j) {
            p0 += lrelu(xs[j] + xrv[j]) * atv[j];
            p1 += lrelu(xs[j + 4] + xrv[j + 4]) * atv[j + 4];
        }
        float p = red8_dpp(p0 + p1);            // alpha for this lane's head
        float w = __expf(fminf(p, 60.f));
        l += w;
#pragma unroll
        for (int j = 0; j < 8; ++j) acc8[j] += w * xs[j];
        u0 = u1; u1 = u2;
    }
    float inv = 1.f / (l + 1e-16f);
    const float* brow = b1 + lane * 8;
    ushort8_t vout;
#pragma unroll
    for (int j = 0; j < 8; ++j) {
        float v = acc8[j] * inv + brow[j];
        v = (v > 0.f) ? v : (__expf(v) - 1.f);  // elu (fast exp)
        vout[j] = f2bf(v);
    }
    *reinterpret_cast<ushort8_t*>(h1b + (size_t)n * 512 + lane * 8) = vout;
}

// ---------------- layer 2: MFMA GEMM ----------------

// M=10000, N=64, K=512 bf16. 64-row tiles, 4 waves (wave = 16 rows),
// 1x4 fragments/wave. Grid: 157 blocks.
__global__ __launch_bounds__(256) void k_mfma2(const unsigned short* __restrict__ h1b,
        const unsigned short* __restrict__ Bt2, float* __restrict__ xw2) {
    __shared__ unsigned short Hs[64 * 40];
    __shared__ unsigned short Ws[64 * 40];
    int t = threadIdx.x;
    int wave = t >> 6, L = t & 63;
    int row0 = blockIdx.x * 64;
    int q = L >> 4, rr = L & 15;
    floatx4 acc[4];
#pragma unroll
    for (int j = 0; j < 4; ++j) acc[j] = (floatx4){0.f, 0.f, 0.f, 0.f};
    int ra = t >> 2, ka = (t & 3) * 8;       // 64 rows x 4 chunks = 1/thread
    int gma = row0 + ra; gma = (gma < N_NODES) ? gma : (N_NODES - 1);
    for (int kc = 0; kc < 512; kc += 32) {
        __syncthreads();
        *reinterpret_cast<uint4*>(&Hs[ra * 40 + ka]) =
            *reinterpret_cast<const uint4*>(h1b + (size_t)gma * 512 + kc + ka);
        *reinterpret_cast<uint4*>(&Ws[ra * 40 + ka]) =
            *reinterpret_cast<const uint4*>(Bt2 + (size_t)ra * 512 + kc + ka);
        __syncthreads();
        short8 af = *reinterpret_cast<const short8*>(
            &Hs[(wave * 16 + rr) * 40 + q * 8]);
#pragma unroll
        for (int j = 0; j < 4; ++j) {
            short8 bf = *reinterpret_cast<const short8*>(
                &Ws[(j * 16 + rr) * 40 + q * 8]);
            acc[j] = __builtin_amdgcn_mfma_f32_16x16x32_bf16(af, bf, acc[j], 0, 0, 0);
        }
    }
    // epilogue: col=lane&15, row=(lane>>4)*4+reg
#pragma unroll
    for (int j = 0; j < 4; ++j) {
        int gc = j * 16 + rr;
#pragma unroll
        for (int r = 0; r < 4; ++r) {
            int gr = row0 + wave * 16 + q * 4 + r;
            if (gr < N_NODES) xw2[(size_t)gr * 64 + gc] = acc[j][r];
        }
    }
}

// Fused edge+node layer 2 + log_softmax: block = 4 nodes, wave = node,
// barrier-free. Full-chunk loop + masked tail. (xw2 is 2.5 MB, L2-hot.)
__global__ __launch_bounds__(256) void k_node2f(const int* __restrict__ offs,
        const int* __restrict__ ssrc, const float* __restrict__ xw2,
        const float* __restrict__ att2, const float* __restrict__ b2,
        float* __restrict__ out) {
    int t = threadIdx.x;
    int wave = t >> 6, lane = t & 63;
    int n = blockIdx.x * 4 + wave;
    if (n >= N_NODES) return;
    int ej = lane >> 3;
    int cg = lane & 7;
    int beg = offs[n], dcnt = offs[n + 1] - beg;
    float4 xr = *reinterpret_cast<const float4*>(
                    xw2 + (size_t)n * 64 + 32 + cg * 4);
    float4 at = *reinterpret_cast<const float4*>(att2 + cg * 4);
    float l = 0.f;
    float4 ac = {0.f, 0.f, 0.f, 0.f};
    const int* sp = ssrc + beg;
    const char* xwbase = reinterpret_cast<const char*>(xw2) + cg * 16;
    auto ld_off = [&](int i1) -> int {
        int i1c = (i1 < dcnt) ? i1 : (dcnt - 1);
        return sp[i1c] << 8;
    };
    auto ld_row = [&](int off) -> float4 {
        return *reinterpret_cast<const float4*>(xwbase + off);
    };
    int full = dcnt & ~15;
    float4 uA = ld_row(ld_off(ej));
    float4 uB = ld_row(ld_off(8 + ej));
    int oA1 = ld_off(16 + ej), oB1 = ld_off(24 + ej);
    for (int base = 0; base < full; base += 16) {
        float4 uA1 = ld_row(oA1), uB1 = ld_row(oB1);
        int oA2 = ld_off(base + 32 + ej);
        int oB2 = ld_off(base + 40 + ej);
        float pA0 = lrelu(uA.x + xr.x) * at.x + lrelu(uA.z + xr.z) * at.z;
        float pA1 = lrelu(uA.y + xr.y) * at.y + lrelu(uA.w + xr.w) * at.w;
        float pB0 = lrelu(uB.x + xr.x) * at.x + lrelu(uB.z + xr.z) * at.z;
        float pB1 = lrelu(uB.y + xr.y) * at.y + lrelu(uB.w + xr.w) * at.w;
        float wA = __expf(fminf(red8_dpp(pA0 + pA1), 60.f));
        float wB = __expf(fminf(red8_dpp(pB0 + pB1), 60.f));
        l += wA + wB;
        ac.x += wA * uA.x + wB * uB.x;
        ac.y += wA * uA.y + wB * uB.y;
        ac.z += wA * uA.z + wB * uB.z;
        ac.w += wA * uA.w + wB * uB.w;
        uA = uA1; uB = uB1; oA1 = oA2; oB1 = oB2;
    }
    if (full < dcnt) {
        float pA0 = lrelu(uA.x + xr.x) * at.x + lrelu(uA.z + xr.z) * at.z;
        float pA1 = lrelu(uA.y + xr.y) * at.y + lrelu(uA.w + xr.w) * at.w;
        float pB0 = lrelu(uB.x + xr.x) * at.x + lrelu(uB.z + xr.z) * at.z;
        float pB1 = lrelu(uB.y + xr.y) * at.y + lrelu(uB.w + xr.w) * at.w;
        float pA = red8_dpp(pA0 + pA1);
        float pB = red8_dpp(pB0 + pB1);
        if (full + ej >= dcnt)     pA = -1e30f;
        if (full + 8 + ej >= dcnt) pB = -1e30f;
        float wA = __expf(fminf(pA, 60.f));
        float wB = __expf(fminf(pB, 60.f));
        l += wA + wB;
        ac.x += wA * uA.x + wB * uB.x;
        ac.y += wA * uA.y + wB * uB.y;
        ac.z += wA * uA.z + wB * uB.z;
        ac.w += wA * uA.w + wB * uB.w;
    }
    l = ror8_add(l); l += __shfl_xor(l, 16); l += __shfl_xor(l, 32);
    ac.x = ror8_add(ac.x); ac.x += __shfl_xor(ac.x, 16); ac.x += __shfl_xor(ac.x, 32);
    ac.y = ror8_add(ac.y); ac.y += __shfl_xor(ac.y, 16); ac.y += __shfl_xor(ac.y, 32);
    ac.z = ror8_add(ac.z); ac.z += __shfl_xor(ac.z, 16); ac.z += __shfl_xor(ac.z, 32);
    ac.w = ror8_add(ac.w); ac.w += __shfl_xor(ac.w, 16); ac.w += __shfl_xor(ac.w, 32);
    float inv = 1.f / (l + 1e-16f);
    float4 bb = *reinterpret_cast<const float4*>(b2 + cg * 4);
    float4 v;
    v.x = ac.x * inv + bb.x; v.y = ac.y * inv + bb.y;
    v.z = ac.z * inv + bb.z; v.w = ac.w * inv + bb.w;
    // log_softmax over 32 channels (8-lane DPP; ej groups identical)
    float mx = red8max_dpp(fmaxf(fmaxf(v.x, v.y), fmaxf(v.z, v.w)));
    float se = red8_dpp(__expf(v.x - mx) + __expf(v.y - mx)
                      + __expf(v.z - mx) + __expf(v.w - mx));
    float ls = __logf(se);
    v.x = v.x - mx - ls; v.y = v.y - mx - ls;
    v.z = v.z - mx - ls; v.w = v.w - mx - ls;
    if (ej == 0)
        *reinterpret_cast<float4*>(out + (size_t)n * 32 + cg * 4) = v;
}

// ---------------- launch ----------------

extern "C" void kernel_launch(void* const* d_in, const int* in_sizes, int n_in,
                              void* d_out, int out_size, void* d_ws, size_t ws_size,
                              hipStream_t stream) {
    (void)in_sizes; (void)n_in; (void)out_size; (void)ws_size;
    const float* x    = (const float*)d_in[0];
    const int*   ei   = (const int*)d_in[1];
    const float* W1l  = (const float*)d_in[2];
    const float* W1r  = (const float*)d_in[3];
    const float* att1 = (const float*)d_in[4];
    const float* b1   = (const float*)d_in[5];
    const float* W2l  = (const float*)d_in[6];
    const float* W2r  = (const float*)d_in[7];
    const float* att2 = (const float*)d_in[8];
    const float* b2   = (const float*)d_in[9];
    float* outp = (float*)d_out;

    char* ws = (char*)d_ws;
    size_t o = 0;
    auto alloc = [&](size_t bytes) {
        char* p = ws + o;
        o = (o + bytes + 255) & ~(size_t)255;
        return p;
    };
    unsigned short* xl1b = (unsigned short*)alloc((size_t)N_NODES * 512 * 2);
    unsigned short* xr1b = (unsigned short*)alloc((size_t)N_NODES * 512 * 2);
    unsigned short* h1b  = (unsigned short*)alloc((size_t)N_NODES * 512 * 2);
    float* xw2    = (float*)alloc((size_t)N_NODES * 64 * 4);
    unsigned short* Abf = (unsigned short*)alloc((size_t)N_NODES * 512 * 2);
    unsigned short* Bbf = (unsigned short*)alloc((size_t)1024 * 512 * 2);
    unsigned short* Bt2 = (unsigned short*)alloc((size_t)64 * 512 * 2);
    int*   deg    = (int*)alloc((size_t)N_NODES * 4);
    int*   offs   = (int*)alloc((size_t)(N_NODES + 1) * 4);
    int*   ssrc   = (int*)alloc((size_t)ET * 4);

    hipMemsetAsync(deg, 0, (size_t)N_NODES * 4, stream);

    k_prep   <<<NB_COUNT + NB_CONVX + NB_CONVW + NB_CONVW2, 256, 0, stream>>>(
                 ei, deg, x, Abf, W1l, W1r, Bbf, W2l, W2r, Bt2);
    k_scan   <<<1,                    1024, 0, stream>>>(deg, offs);
    k_scatter<<<(ET + 255) / 256,      256, 0, stream>>>(ei, offs, deg, ssrc);
    k_mfma1  <<<dim3(79, 8),           256, 0, stream>>>(Abf, Bbf, xl1b, xr1b);
    k_node1f <<<(N_NODES + 3) / 4,     256, 0, stream>>>(offs, ssrc, xl1b, xr1b, att1, b1, h1b);
    k_mfma2  <<<(N_NODES + 63) / 64,   256, 0, stream>>>(h1b, Bt2, xw2);
    k_node2f <<<(N_NODES + 3) / 4,     256, 0, stream>>>(offs, ssrc, xw2, att2, b2, outp);
}

// Round 21
// 221.406 us; speedup vs baseline: 1.3545x; 1.0387x over previous
//
#include <hip/hip_runtime.h>
#include <hip/hip_bf16.h>

// GATv2 x2 on MI355X — R21: pure-bf16 layer-1 GEMM (K=256, no split-lo).
//  Evidence: absmax pinned at 0.015625 (bf16-ULP comparison floor) through
//  R10/R17/R19 precision cuts of the same scale. Dropping the residual
//  halves mfma1's K-iters and its A-staging traffic (80 -> 40 MB).
//  Node kernels unchanged from R20 (coalesced-row gather, lane-owned chans).

constexpr int N_NODES = 10000;
constexpr int N_EDGES = 320000;
constexpr int ET      = N_EDGES + N_NODES;   // 330000 incl. self loops
constexpr float NEG_SLOPE = 0.2f;

constexpr int NB_COUNT  = (ET + 255) / 256;          // 1290
constexpr int NB_CONVX  = (N_NODES * 64) / 256;      // 2500
constexpr int NB_CONVW  = (1024 * 64) / 256;         // 256
constexpr int NB_CONVW2 = (64 * 128) / 256;          // 32

typedef __attribute__((ext_vector_type(8))) short short8;
typedef __attribute__((ext_vector_type(8))) unsigned short ushort8_t;
typedef __attribute__((ext_vector_type(4))) float floatx4;

__device__ __forceinline__ float lrelu(float a) {
    return fmaxf(a, NEG_SLOPE * a);
}
__device__ __forceinline__ unsigned short f2bf(float f) {   // RNE
    unsigned u = __float_as_uint(f);
    unsigned r = u + 0x7FFFu + ((u >> 16) & 1u);
    return (unsigned short)(r >> 16);
}
__device__ __forceinline__ float bf2f(unsigned short h) {
    return __uint_as_float((unsigned)h << 16);
}
// sum over each aligned group of 8 lanes, result in all 8 (pure VALU)
__device__ __forceinline__ float red8_dpp(float p) {
    int x;
    x = __builtin_amdgcn_update_dpp(0, __float_as_int(p), 0xB1, 0xF, 0xF, true);
    p += __int_as_float(x);                  // quad_perm [1,0,3,2]
    x = __builtin_amdgcn_update_dpp(0, __float_as_int(p), 0x4E, 0xF, 0xF, true);
    p += __int_as_float(x);                  // quad_perm [2,3,0,1]
    x = __builtin_amdgcn_update_dpp(0, __float_as_int(p), 0x141, 0xF, 0xF, true);
    p += __int_as_float(x);                  // row_half_mirror
    return p;
}
__device__ __forceinline__ float red8max_dpp(float p) {
    int x;
    x = __builtin_amdgcn_update_dpp(0, __float_as_int(p), 0xB1, 0xF, 0xF, true);
    p = fmaxf(p, __int_as_float(x));
    x = __builtin_amdgcn_update_dpp(0, __float_as_int(p), 0x4E, 0xF, 0xF, true);
    p = fmaxf(p, __int_as_float(x));
    x = __builtin_amdgcn_update_dpp(0, __float_as_int(p), 0x141, 0xF, 0xF, true);
    p = fmaxf(p, __int_as_float(x));
    return p;
}
// pairwise add with lane^8 partner (row_ror:8 within 16-lane rows)
__device__ __forceinline__ float ror8_add(float p) {
    int x = __builtin_amdgcn_update_dpp(0, __float_as_int(p), 0x128, 0xF, 0xF, true);
    return p + __int_as_float(x);
}

// ------- fused prep: deg count + conv_x + conv_w1 + conv_w2 -------

__global__ __launch_bounds__(256) void k_prep(const int* __restrict__ ei,
        int* __restrict__ deg, const float* __restrict__ x,
        unsigned short* __restrict__ A, const float* __restrict__ Wl,
        const float* __restrict__ Wr, unsigned short* __restrict__ Bt,
        const float* __restrict__ W2l, const float* __restrict__ W2r,
        unsigned short* __restrict__ Bt2) {
    int b = blockIdx.x, t = threadIdx.x;
    if (b < NB_COUNT) {
        int e = b * 256 + t;
        if (e >= ET) return;
        int d = (e < N_EDGES) ? ei[N_EDGES + e] : (e - N_EDGES);
        atomicAdd(&deg[d], 1);
    } else if (b < NB_COUNT + NB_CONVX) {
        int idx = (b - NB_COUNT) * 256 + t;       // < N_NODES*64
        int m = idx >> 6, kg = (idx & 63) << 2;
        float4 v = *reinterpret_cast<const float4*>(x + (size_t)m * 256 + kg);
        ushort4 hi = make_ushort4(f2bf(v.x), f2bf(v.y), f2bf(v.z), f2bf(v.w));
        *reinterpret_cast<ushort4*>(A + (size_t)m * 256 + kg) = hi;
    } else if (b < NB_COUNT + NB_CONVX + NB_CONVW) {
        int idx = (b - NB_COUNT - NB_CONVX) * 256 + t;   // < 1024*64
        int n = idx >> 6, kg = (idx & 63) << 2;
        const float* src = (n < 512) ? (Wl + n) : (Wr + (n - 512));
        float v0 = src[(size_t)(kg + 0) * 512];
        float v1 = src[(size_t)(kg + 1) * 512];
        float v2 = src[(size_t)(kg + 2) * 512];
        float v3 = src[(size_t)(kg + 3) * 512];
        ushort4 hi = make_ushort4(f2bf(v0), f2bf(v1), f2bf(v2), f2bf(v3));
        *reinterpret_cast<ushort4*>(Bt + (size_t)n * 256 + kg) = hi;
    } else {
        int idx = (b - NB_COUNT - NB_CONVX - NB_CONVW) * 256 + t;  // < 64*128
        int j = idx >> 7, kg = (idx & 127) << 2;
        const float* src = (j < 32) ? (W2l + j) : (W2r + (j - 32));
        float v0 = src[(size_t)(kg + 0) * 32];
        float v1 = src[(size_t)(kg + 1) * 32];
        float v2 = src[(size_t)(kg + 2) * 32];
        float v3 = src[(size_t)(kg + 3) * 32];
        ushort4 hi = make_ushort4(f2bf(v0), f2bf(v1), f2bf(v2), f2bf(v3));
        *reinterpret_cast<ushort4*>(Bt2 + (size_t)j * 512 + kg) = hi;
    }
}

// ---------------- CSR scan + scatter ----------------

__global__ __launch_bounds__(1024) void k_scan(const int* __restrict__ deg,
                                               int* __restrict__ offs) {
    __shared__ int part[1024];
    const int CH = 10;                       // ceil(10000/1024)
    int t = threadIdx.x;
    int base = t * CH;
    int loc[CH];
    int s = 0;
    for (int i = 0; i < CH; ++i) {
        int idx = base + i;
        int v = (idx < N_NODES) ? deg[idx] : 0;
        loc[i] = s; s += v;
    }
    part[t] = s;
    __syncthreads();
    for (int o = 1; o < 1024; o <<= 1) {
        int add = (t >= o) ? part[t - o] : 0;
        __syncthreads();
        part[t] += add;
        __syncthreads();
    }
    int excl = part[t] - s;
    for (int i = 0; i < CH; ++i) {
        int idx = base + i;
        if (idx < N_NODES) offs[idx] = excl + loc[i];
    }
    if (t == 1023) offs[N_NODES] = part[1023];
}

// deg doubles as countdown cursor: pos = offs[d] + (--deg[d])
__global__ void k_scatter(const int* __restrict__ ei, const int* __restrict__ offs,
                          int* __restrict__ deg, int* __restrict__ ssrc) {
    int e = blockIdx.x * 256 + threadIdx.x;
    if (e >= ET) return;
    int s, d;
    if (e < N_EDGES) { s = ei[e]; d = ei[N_EDGES + e]; }
    else             { s = d = e - N_EDGES; }
    int pos = offs[d] + atomicAdd(&deg[d], -1) - 1;
    ssrc[pos] = s;
}

// ---------------- layer 1 MFMA GEMM ----------------

// 128x128 tile, M=10000 N=1024 K=256 (pure bf16), grid (79,8), 4 waves/block.
__global__ __launch_bounds__(256) void k_mfma1(const unsigned short* __restrict__ A,
        const unsigned short* __restrict__ Bt, unsigned short* __restrict__ xl1b,
        unsigned short* __restrict__ xr1b) {
    __shared__ unsigned short As[128 * 40];   // stride 40: 2-way max = free
    __shared__ unsigned short Bs[128 * 40];
    int t = threadIdx.x;
    int wave = t >> 6, L = t & 63;
    int wm = wave & 1, wn = wave >> 1;
    int row0 = blockIdx.x * 128, n0 = blockIdx.y * 128;
    int q = L >> 4, rr = L & 15;
    floatx4 acc[4][4];
#pragma unroll
    for (int i = 0; i < 4; ++i)
#pragma unroll
        for (int j = 0; j < 4; ++j) acc[i][j] = (floatx4){0.f, 0.f, 0.f, 0.f};
    int ra = t >> 2,        ka = (t & 3) * 8;
    int rb = (t + 256) >> 2, kb = ((t + 256) & 3) * 8;
    int gma = row0 + ra; gma = (gma < N_NODES) ? gma : (N_NODES - 1);
    int gmb = row0 + rb; gmb = (gmb < N_NODES) ? gmb : (N_NODES - 1);
    for (int kc = 0; kc < 256; kc += 32) {
        __syncthreads();
        *reinterpret_cast<uint4*>(&As[ra * 40 + ka]) =
            *reinterpret_cast<const uint4*>(A + (size_t)gma * 256 + kc + ka);
        *reinterpret_cast<uint4*>(&As[rb * 40 + kb]) =
            *reinterpret_cast<const uint4*>(A + (size_t)gmb * 256 + kc + kb);
        *reinterpret_cast<uint4*>(&Bs[ra * 40 + ka]) =
            *reinterpret_cast<const uint4*>(Bt + (size_t)(n0 + ra) * 256 + kc + ka);
        *reinterpret_cast<uint4*>(&Bs[rb * 40 + kb]) =
            *reinterpret_cast<const uint4*>(Bt + (size_t)(n0 + rb) * 256 + kc + kb);
        __syncthreads();
        short8 af[4], bf[4];
#pragma unroll
        for (int st = 0; st < 4; ++st)
            af[st] = *reinterpret_cast<const short8*>(
                &As[(wm * 64 + st * 16 + rr) * 40 + q * 8]);
#pragma unroll
        for (int st = 0; st < 4; ++st)
            bf[st] = *reinterpret_cast<const short8*>(
                &Bs[(wn * 64 + st * 16 + rr) * 40 + q * 8]);
#pragma unroll
        for (int i = 0; i < 4; ++i)
#pragma unroll
            for (int j = 0; j < 4; ++j)
                acc[i][j] = __builtin_amdgcn_mfma_f32_16x16x32_bf16(
                    af[i], bf[j], acc[i][j], 0, 0, 0);
    }
    // epilogue: C/D layout col=lane&15, row=(lane>>4)*4+reg  [m89/m91]
#pragma unroll
    for (int j = 0; j < 4; ++j) {
        int gc = n0 + wn * 64 + j * 16 + rr;
        unsigned short* dst = (gc < 512) ? xl1b : xr1b;
        int col = (gc < 512) ? gc : (gc - 512);
#pragma unroll
        for (int i = 0; i < 4; ++i)
#pragma unroll
            for (int r = 0; r < 4; ++r) {
                int gr = row0 + wm * 64 + i * 16 + q * 4 + r;
                if (gr < N_NODES)
                    dst[(size_t)gr * 512 + col] = f2bf(acc[i][j][r]);
            }
    }
}

// Fused edge+node layer 1 — wave = node (block = 4 nodes, barrier-free).
// Lane l = (head l>>3, cg l&7): one coalesced 1KB row load per edge,
// red8_dpp head-alphas, lane-exclusive channels, no final reduce/masks.
__global__ __launch_bounds__(256) void k_node1f(const int* __restrict__ offs,
        const int* __restrict__ ssrc, const unsigned short* __restrict__ xl1b,
        const unsigned short* __restrict__ xr1b, const float* __restrict__ att1,
        const float* __restrict__ b1, unsigned short* __restrict__ h1b) {
    int t = threadIdx.x;
    int wave = t >> 6, lane = t & 63;
    int n = blockIdx.x * 4 + wave;
    if (n >= N_NODES) return;
    int beg = offs[n], dcnt = offs[n + 1] - beg;
    float xrv[8], atv[8];
    {
        ushort8_t xru = *reinterpret_cast<const ushort8_t*>(
            xr1b + (size_t)n * 512 + lane * 8);
        const float* atrow = att1 + lane * 8;
        float4 c0 = *reinterpret_cast<const float4*>(atrow);
        float4 c1 = *reinterpret_cast<const float4*>(atrow + 4);
#pragma unroll
        for (int i = 0; i < 8; ++i) xrv[i] = bf2f(xru[i]);
        atv[0]=c0.x; atv[1]=c0.y; atv[2]=c0.z; atv[3]=c0.w;
        atv[4]=c1.x; atv[5]=c1.y; atv[6]=c1.z; atv[7]=c1.w;
    }
    float l = 0.f;
    float acc8[8];
#pragma unroll
    for (int i = 0; i < 8; ++i) acc8[i] = 0.f;
    const int* sp = ssrc + beg;
    const char* xlbase = reinterpret_cast<const char*>(xl1b) + lane * 16;
    auto ld_off = [&](int i) -> int {
        int ic = (i < dcnt) ? i : (dcnt - 1);   // dcnt >= 1 (self loop)
        return sp[ic] << 10;
    };
    auto ld_row = [&](int off) -> ushort8_t {
        return *reinterpret_cast<const ushort8_t*>(xlbase + off);
    };
    ushort8_t u0 = ld_row(ld_off(0));
    ushort8_t u1 = ld_row(ld_off(1));
    for (int i = 0; i < dcnt; ++i) {
        ushort8_t u2 = ld_row(ld_off(i + 2));   // depth-2 prefetch
        float xs[8];
#pragma unroll
        for (int j = 0; j < 8; ++j) xs[j] = bf2f(u0[j]);
        float p0 = 0.f, p1 = 0.f;
#pragma unroll
        for (int j = 0; j < 4; ++j) {
            p0 += lrelu(xs[j] + xrv[j]) * atv[j];
            p1 += lrelu(xs[j + 4] + xrv[j + 4]) * atv[j + 4];
        }
        float p = red8_dpp(p0 + p1);            // alpha for this lane's head
        float w = __expf(fminf(p, 60.f));
        l += w;
#pragma unroll
        for (int j = 0; j < 8; ++j) acc8[j] += w * xs[j];
        u0 = u1; u1 = u2;
    }
    float inv = 1.f / (l + 1e-16f);
    const float* brow = b1 + lane * 8;
    ushort8_t vout;
#pragma unroll
    for (int j = 0; j < 8; ++j) {
        float v = acc8[j] * inv + brow[j];
        v = (v > 0.f) ? v : (__expf(v) - 1.f);  // elu (fast exp)
        vout[j] = f2bf(v);
    }
    *reinterpret_cast<ushort8_t*>(h1b + (size_t)n * 512 + lane * 8) = vout;
}

// ---------------- layer 2: MFMA GEMM ----------------

// M=10000, N=64, K=512 bf16. 64-row tiles, 4 waves (wave = 16 rows).
__global__ __launch_bounds__(256) void k_mfma2(const unsigned short* __restrict__ h1b,
        const unsigned short* __restrict__ Bt2, float* __restrict__ xw2) {
    __shared__ unsigned short Hs[64 * 40];
    __shared__ unsigned short Ws[64 * 40];
    int t = threadIdx.x;
    int wave = t >> 6, L = t & 63;
    int row0 = blockIdx.x * 64;
    int q = L >> 4, rr = L & 15;
    floatx4 acc[4];
#pragma unroll
    for (int j = 0; j < 4; ++j) acc[j] = (floatx4){0.f, 0.f, 0.f, 0.f};
    int ra = t >> 2, ka = (t & 3) * 8;       // 64 rows x 4 chunks = 1/thread
    int gma = row0 + ra; gma = (gma < N_NODES) ? gma : (N_NODES - 1);
    for (int kc = 0; kc < 512; kc += 32) {
        __syncthreads();
        *reinterpret_cast<uint4*>(&Hs[ra * 40 + ka]) =
            *reinterpret_cast<const uint4*>(h1b + (size_t)gma * 512 + kc + ka);
        *reinterpret_cast<uint4*>(&Ws[ra * 40 + ka]) =
            *reinterpret_cast<const uint4*>(Bt2 + (size_t)ra * 512 + kc + ka);
        __syncthreads();
        short8 af = *reinterpret_cast<const short8*>(
            &Hs[(wave * 16 + rr) * 40 + q * 8]);
#pragma unroll
        for (int j = 0; j < 4; ++j) {
            short8 bf = *reinterpret_cast<const short8*>(
                &Ws[(j * 16 + rr) * 40 + q * 8]);
            acc[j] = __builtin_amdgcn_mfma_f32_16x16x32_bf16(af, bf, acc[j], 0, 0, 0);
        }
    }
    // epilogue: col=lane&15, row=(lane>>4)*4+reg
#pragma unroll
    for (int j = 0; j < 4; ++j) {
        int gc = j * 16 + rr;
#pragma unroll
        for (int r = 0; r < 4; ++r) {
            int gr = row0 + wave * 16 + q * 4 + r;
            if (gr < N_NODES) xw2[(size_t)gr * 64 + gc] = acc[j][r];
        }
    }
}

// Fused edge+node layer 2 + log_softmax: block = 4 nodes, wave = node,
// barrier-free. Full-chunk loop + masked tail. (xw2 is 2.5 MB, L2-hot.)
__global__ __launch_bounds__(256) void k_node2f(const int* __restrict__ offs,
        const int* __restrict__ ssrc, const float* __restrict__ xw2,
        const float* __restrict__ att2, const float* __restrict__ b2,
        float* __restrict__ out) {
    int t = threadIdx.x;
    int wave = t >> 6, lane = t & 63;
    int n = blockIdx.x * 4 + wave;
    if (n >= N_NODES) return;
    int ej = lane >> 3;
    int cg = lane & 7;
    int beg = offs[n], dcnt = offs[n + 1] - beg;
    float4 xr = *reinterpret_cast<const float4*>(
                    xw2 + (size_t)n * 64 + 32 + cg * 4);
    float4 at = *reinterpret_cast<const float4*>(att2 + cg * 4);
    float l = 0.f;
    float4 ac = {0.f, 0.f, 0.f, 0.f};
    const int* sp = ssrc + beg;
    const char* xwbase = reinterpret_cast<const char*>(xw2) + cg * 16;
    auto ld_off = [&](int i1) -> int {
        int i1c = (i1 < dcnt) ? i1 : (dcnt - 1);
        return sp[i1c] << 8;
    };
    auto ld_row = [&](int off) -> float4 {
        return *reinterpret_cast<const float4*>(xwbase + off);
    };
    int full = dcnt & ~15;
    float4 uA = ld_row(ld_off(ej));
    float4 uB = ld_row(ld_off(8 + ej));
    int oA1 = ld_off(16 + ej), oB1 = ld_off(24 + ej);
    for (int base = 0; base < full; base += 16) {
        float4 uA1 = ld_row(oA1), uB1 = ld_row(oB1);
        int oA2 = ld_off(base + 32 + ej);
        int oB2 = ld_off(base + 40 + ej);
        float pA0 = lrelu(uA.x + xr.x) * at.x + lrelu(uA.z + xr.z) * at.z;
        float pA1 = lrelu(uA.y + xr.y) * at.y + lrelu(uA.w + xr.w) * at.w;
        float pB0 = lrelu(uB.x + xr.x) * at.x + lrelu(uB.z + xr.z) * at.z;
        float pB1 = lrelu(uB.y + xr.y) * at.y + lrelu(uB.w + xr.w) * at.w;
        float wA = __expf(fminf(red8_dpp(pA0 + pA1), 60.f));
        float wB = __expf(fminf(red8_dpp(pB0 + pB1), 60.f));
        l += wA + wB;
        ac.x += wA * uA.x + wB * uB.x;
        ac.y += wA * uA.y + wB * uB.y;
        ac.z += wA * uA.z + wB * uB.z;
        ac.w += wA * uA.w + wB * uB.w;
        uA = uA1; uB = uB1; oA1 = oA2; oB1 = oB2;
    }
    if (full < dcnt) {
        float pA0 = lrelu(uA.x + xr.x) * at.x + lrelu(uA.z + xr.z) * at.z;
        float pA1 = lrelu(uA.y + xr.y) * at.y + lrelu(uA.w + xr.w) * at.w;
        float pB0 = lrelu(uB.x + xr.x) * at.x + lrelu(uB.z + xr.z) * at.z;
        float pB1 = lrelu(uB.y + xr.y) * at.y + lrelu(uB.w + xr.w) * at.w;
        float pA = red8_dpp(pA0 + pA1);
        float pB = red8_dpp(pB0 + pB1);
        if (full + ej >= dcnt)     pA = -1e30f;
        if (full + 8 + ej >= dcnt) pB = -1e30f;
        float wA = __expf(fminf(pA, 60.f));
        float wB = __expf(fminf(pB, 60.f));
        l += wA + wB;
        ac.x += wA * uA.x + wB * uB.x;
        ac.y += wA * uA.y + wB * uB.y;
        ac.z += wA * uA.z + wB * uB.z;
        ac.w += wA * uA.w + wB * uB.w;
    }
    l = ror8_add(l); l += __shfl_xor(l, 16); l += __shfl_xor(l, 32);
    ac.x = ror8_add(ac.x); ac.x += __shfl_xor(ac.x, 16); ac.x += __shfl_xor(ac.x, 32);
    ac.y = ror8_add(ac.y); ac.y += __shfl_xor(ac.y, 16); ac.y += __shfl_xor(ac.y, 32);
    ac.z = ror8_add(ac.z); ac.z += __shfl_xor(ac.z, 16); ac.z += __shfl_xor(ac.z, 32);
    ac.w = ror8_add(ac.w); ac.w += __shfl_xor(ac.w, 16); ac.w += __shfl_xor(ac.w, 32);
    float inv = 1.f / (l + 1e-16f);
    float4 bb = *reinterpret_cast<const float4*>(b2 + cg * 4);
    float4 v;
    v.x = ac.x * inv + bb.x; v.y = ac.y * inv + bb.y;
    v.z = ac.z * inv + bb.z; v.w = ac.w * inv + bb.w;
    // log_softmax over 32 channels (8-lane DPP; ej groups identical)
    float mx = red8max_dpp(fmaxf(fmaxf(v.x, v.y), fmaxf(v.z, v.w)));
    float se = red8_dpp(__expf(v.x - mx) + __expf(v.y - mx)
                      + __expf(v.z - mx) + __expf(v.w - mx));
    float ls = __logf(se);
    v.x = v.x - mx - ls; v.y = v.y - mx - ls;
    v.z = v.z - mx - ls; v.w = v.w - mx - ls;
    if (ej == 0)
        *reinterpret_cast<float4*>(out + (size_t)n * 32 + cg * 4) = v;
}

// ---------------- launch ----------------

extern "C" void kernel_launch(void* const* d_in, const int* in_sizes, int n_in,
                              void* d_out, int out_size, void* d_ws, size_t ws_size,
                              hipStream_t stream) {
    (void)in_sizes; (void)n_in; (void)out_size; (void)ws_size;
    const float* x    = (const float*)d_in[0];
    const int*   ei   = (const int*)d_in[1];
    const float* W1l  = (const float*)d_in[2];
    const float* W1r  = (const float*)d_in[3];
    const float* att1 = (const float*)d_in[4];
    const float* b1   = (const float*)d_in[5];
    const float* W2l  = (const float*)d_in[6];
    const float* W2r  = (const float*)d_in[7];
    const float* att2 = (const float*)d_in[8];
    const float* b2   = (const float*)d_in[9];
    float* outp = (float*)d_out;

    char* ws = (char*)d_ws;
    size_t o = 0;
    auto alloc = [&](size_t bytes) {
        char* p = ws + o;
        o = (o + bytes + 255) & ~(size_t)255;
        return p;
    };
    unsigned short* xl1b = (unsigned short*)alloc((size_t)N_NODES * 512 * 2);
    unsigned short* xr1b = (unsigned short*)alloc((size_t)N_NODES * 512 * 2);
    unsigned short* h1b  = (unsigned short*)alloc((size_t)N_NODES * 512 * 2);
    float* xw2    = (float*)alloc((size_t)N_NODES * 64 * 4);
    unsigned short* Abf = (unsigned short*)alloc((size_t)N_NODES * 256 * 2);
    unsigned short* Bbf = (unsigned short*)alloc((size_t)1024 * 256 * 2);
    unsigned short* Bt2 = (unsigned short*)alloc((size_t)64 * 512 * 2);
    int*   deg    = (int*)alloc((size_t)N_NODES * 4);
    int*   offs   = (int*)alloc((size_t)(N_NODES + 1) * 4);
    int*   ssrc   = (int*)alloc((size_t)ET * 4);

    hipMemsetAsync(deg, 0, (size_t)N_NODES * 4, stream);

    k_prep   <<<NB_COUNT + NB_CONVX + NB_CONVW + NB_CONVW2, 256, 0, stream>>>(
                 ei, deg, x, Abf, W1l, W1r, Bbf, W2l, W2r, Bt2);
    k_scan   <<<1,                    1024, 0, stream>>>(deg, offs);
    k_scatter<<<(ET + 255) / 256,      256, 0, stream>>>(ei, offs, deg, ssrc);
    k_mfma1  <<<dim3(79, 8),           256, 0, stream>>>(Abf, Bbf, xl1b, xr1b);
    k_node1f <<<(N_NODES + 3) / 4,     256, 0, stream>>>(offs, ssrc, xl1b, xr1b, att1, b1, h1b);
    k_mfma2  <<<(N_NODES + 63) / 64,   256, 0, stream>>>(h1b, Bt2, xw2);
    k_node2f <<<(N_NODES + 3) / 4,     256, 0, stream>>>(offs, ssrc, xw2, att2, b2, outp);
}